// Round 5
// baseline (918.538 us; speedup 1.0000x reference)
//
#include <hip/hip_runtime.h>

typedef unsigned short u16;
typedef __attribute__((ext_vector_type(8))) __bf16 bf16x8;
typedef __attribute__((ext_vector_type(4))) float f32x4;

#define LSEQ 4096
#define DMODEL 1024
#define DINNER 2048

__device__ __forceinline__ float bf2f(u16 u) {
  union { unsigned u; float f; } v; v.u = ((unsigned)u) << 16; return v.f;
}
__device__ __forceinline__ u16 f2bf(float f) {
  union { float f; unsigned u; } v; v.f = f;
  unsigned r = v.u + 0x7fffu + ((v.u >> 16) & 1u);
  return (u16)(r >> 16);
}
__device__ __forceinline__ void gload_lds16(const void* g, void* l) {
  __builtin_amdgcn_global_load_lds(
      (__attribute__((address_space(1))) void*)(unsigned long long)g,
      (__attribute__((address_space(3))) void*)(unsigned int)(unsigned long long)l,
      16, 0, 0);
}
__device__ __forceinline__ float sigmoidf_(float v) { return 1.f / (1.f + __expf(-v)); }

// bijective XCD swizzle (nwg % 8 == 0): XCD x gets contiguous swz chunk -> shared A panel
__device__ __forceinline__ void swz_block(int gx, int& bn, int& bm) {
  int lin = blockIdx.x + gridDim.x * blockIdx.y;
  int q = (gridDim.x * gridDim.y) >> 3;
  int s = (lin & 7) * q + (lin >> 3);
  bn = s % gx;
  bm = s / gx;
}

// ---------------- LayerNorm -> bf16 ----------------
__global__ __launch_bounds__(256) void ln_kernel(const float* __restrict__ x,
                                                 const float* __restrict__ w,
                                                 const float* __restrict__ b,
                                                 u16* __restrict__ out) {
  int row = blockIdx.x;
  const float* xr = x + (size_t)row * DMODEL;
  int t = threadIdx.x;
  float4 v = ((const float4*)xr)[t];
  float s = v.x + v.y + v.z + v.w;
  float s2 = v.x * v.x + v.y * v.y + v.z * v.z + v.w * v.w;
  for (int off = 32; off; off >>= 1) {
    s += __shfl_down(s, off);
    s2 += __shfl_down(s2, off);
  }
  __shared__ float ls[4], ls2[4];
  int wid = t >> 6;
  if ((t & 63) == 0) { ls[wid] = s; ls2[wid] = s2; }
  __syncthreads();
  s = ls[0] + ls[1] + ls[2] + ls[3];
  s2 = ls2[0] + ls2[1] + ls2[2] + ls2[3];
  float mu = s * (1.f / DMODEL);
  float var = s2 * (1.f / DMODEL) - mu * mu;
  float rs = rsqrtf(var + 1e-5f);
  float4 wv = ((const float4*)w)[t];
  float4 bv = ((const float4*)b)[t];
  unsigned p0 = (unsigned)f2bf((v.x - mu) * rs * wv.x + bv.x) |
                ((unsigned)f2bf((v.y - mu) * rs * wv.y + bv.y) << 16);
  unsigned p1 = (unsigned)f2bf((v.z - mu) * rs * wv.z + bv.z) |
                ((unsigned)f2bf((v.w - mu) * rs * wv.w + bv.w) << 16);
  ((uint2*)(out + (size_t)row * DMODEL))[t] = make_uint2(p0, p1);
}

// ---------------- transpose + cast f32[K][N] -> bf16[Npad][K], zero-fill ----------------
__global__ __launch_bounds__(256) void tc_kernel(const float* __restrict__ in,
                                                 u16* __restrict__ out,
                                                 int K, int N, int Npad) {
  __shared__ float tile[32][33];
  int n0 = blockIdx.x * 32, k0 = blockIdx.y * 32;
  int tx = threadIdx.x & 31, ty = threadIdx.x >> 5;
  for (int i = ty; i < 32; i += 8) {
    int k = k0 + i, n = n0 + tx;
    tile[i][tx] = (k < K && n < N) ? in[(size_t)k * N + n] : 0.f;
  }
  __syncthreads();
  for (int i = ty; i < 32; i += 8) {
    int n = n0 + i, k = k0 + tx;
    if (n < Npad && k < K) out[(size_t)n * K + k] = f2bf(tile[tx][i]);
  }
}

// =====================================================================================
// v2: 256x256 tile, BK=32, 64KB LDS -> 2 blocks/CU. 4 phases per K-tile.
// A,B each [2 buf][256 rows][32 k] bf16 (16KB/buf). 16B slot swizzle: phys = log ^ (row&3).
// Stage: during tile T, P2 stages B(T+2)->b0, P3 stages A(T+2)->b0 (regions last read at
// P1/P2 of T, closed by their barriers). vmcnt(4) at P3 confirms A(T+1),B(T+1)
// (staged at T-1 P3/P2, FIFO-oldest 4 of 8 in flight) before tile T+1 reads.
// =====================================================================================
__device__ __forceinline__ void stage32(const u16* gbase, int ldK, int kcol0,
                                        u16* lds_base, int w, int ln) {
#pragma unroll
  for (int c = 0; c < 2; ++c) {
    int r0 = c * 128 + w * 16;  // wave-uniform row base; lane ln -> row r0+(ln>>2), slot ln&3
    int rr = ln >> 2;
    int slog = (ln & 3) ^ (rr & 3);
    gload_lds16(gbase + (size_t)(r0 + rr) * ldK + kcol0 + slog * 8, lds_base + r0 * 32);
  }
}

#define LDA32(mh, buf)                                                             \
  _Pragma("unroll") for (int mf = 0; mf < 4; ++mf)                                 \
    a[mf] = *(const bf16x8*)(LA + (buf) * 8192 +                                   \
        (wm * 128 + (mh) * 64 + mf * 16 + lr) * 32 + ((lq ^ (lr & 3)) << 3));

#define LDB32(nh, buf, B_)                                                         \
  _Pragma("unroll") for (int nf = 0; nf < 2; ++nf)                                 \
    B_[nf] = *(const bf16x8*)(LB + (buf) * 8192 +                                  \
        (wn * 64 + (nh) * 32 + nf * 16 + lr) * 32 + ((lq ^ (lr & 3)) << 3));

#define MFMA_Q32(mh, nh, B_)                                                       \
  __builtin_amdgcn_s_setprio(1);                                                   \
  _Pragma("unroll") for (int mf = 0; mf < 4; ++mf)                                 \
  _Pragma("unroll") for (int nf = 0; nf < 2; ++nf)                                 \
    acc[(mh) * 4 + mf][(nh) * 2 + nf] = __builtin_amdgcn_mfma_f32_16x16x32_bf16(   \
        a[mf], B_[nf], acc[(mh) * 4 + mf][(nh) * 2 + nf], 0, 0, 0);                \
  __builtin_amdgcn_s_setprio(0);

template <int OUT_BF16, int EPI>  // EPI: 0 none, 2 silu col>=cthresh
__global__ __launch_bounds__(512, 4) void gemm32(const u16* __restrict__ A,
                                                 const u16* __restrict__ Bt,
                                                 void* __restrict__ Cout,
                                                 int M, int N, int K, int cthresh) {
  __shared__ alignas(16) u16 lds[32768];
  u16* LA = lds;
  u16* LB = lds + 16384;
  int t = threadIdx.x;
  int w = t >> 6, ln = t & 63;
  int wm = w >> 2, wn = w & 3;
  int bn, bm;
  swz_block(gridDim.x, bn, bm);
  int lr = ln & 15, lq = ln >> 4;
  int NT = K >> 5;
  const u16* Ag = A + (size_t)bm * 256 * K;
  const u16* Bg = Bt + (size_t)bn * 256 * K;
  f32x4 acc[8][4] = {};
  bf16x8 a[4], bbl[2], bbh[2];

  // prologue: A(0),B(0),B(1),A(1) so vmcnt(4) confirms tile0 (oldest 4 loads)
  stage32(Ag, K, 0, LA, w, ln);
  stage32(Bg, K, 0, LB, w, ln);
  int k1 = NT > 1 ? 1 : 0;
  stage32(Bg, K, k1 * 32, LB + 8192, w, ln);
  stage32(Ag, K, k1 * 32, LA + 8192, w, ln);
  asm volatile("s_waitcnt vmcnt(4)" ::: "memory");
  __builtin_amdgcn_s_barrier();

  for (int T = 0; T < NT; ++T) {
    int b0 = T & 1;
    int kt2 = (T + 2 < NT) ? T + 2 : NT - 1;
    // P0: (m-lo, n-lo)
    LDA32(0, b0);
    LDB32(0, b0, bbl);
    __builtin_amdgcn_s_barrier();
    asm volatile("s_waitcnt lgkmcnt(0)" ::: "memory");
    MFMA_Q32(0, 0, bbl);
    __builtin_amdgcn_s_barrier();
    // P1: (m-lo, n-hi)
    LDB32(1, b0, bbh);
    __builtin_amdgcn_s_barrier();
    asm volatile("s_waitcnt lgkmcnt(0)" ::: "memory");
    MFMA_Q32(0, 1, bbh);
    __builtin_amdgcn_s_barrier();
    // P2: (m-hi, n-hi); stage B(T+2) -> b0 (B-unit of b0 last read at P1, closed)
    LDA32(1, b0);
    stage32(Bg, K, kt2 * 32, LB + b0 * 8192, w, ln);
    __builtin_amdgcn_s_barrier();
    asm volatile("s_waitcnt lgkmcnt(0)" ::: "memory");
    MFMA_Q32(1, 1, bbh);
    __builtin_amdgcn_s_barrier();
    // P3: (m-hi, n-lo); stage A(T+2) -> b0 (A-unit of b0 last read at P2, closed)
    stage32(Ag, K, kt2 * 32, LA + b0 * 8192, w, ln);
    asm volatile("s_waitcnt vmcnt(4)" ::: "memory");
    __builtin_amdgcn_s_barrier();
    MFMA_Q32(1, 0, bbl);
    __builtin_amdgcn_s_barrier();
  }

  int crow0 = bm * 256 + wm * 128;
  int ccol0 = bn * 256 + wn * 64;
#pragma unroll
  for (int mf = 0; mf < 8; ++mf)
#pragma unroll
    for (int nf = 0; nf < 4; ++nf)
#pragma unroll
      for (int r = 0; r < 4; ++r) {
        int row = crow0 + mf * 16 + lq * 4 + r;
        int col = ccol0 + nf * 16 + lr;
        float v = acc[mf][nf][r];
        if (EPI == 2 && col >= cthresh) v = v * sigmoidf_(v);
        if (OUT_BF16)
          ((u16*)Cout)[(size_t)row * N + col] = f2bf(v);
        else
          ((float*)Cout)[(size_t)row * N + col] = v;
      }
}

// =====================================================================================
// v1: 256x256, BK=64, 128KB LDS, 8-phase (round-4 verified) — split-K x2, f32 partials
// =====================================================================================
__device__ __forceinline__ void stage8(const u16* grow0, int ld, int kcol0,
                                       u16* lds_u, int ln) {
  int rr = ln >> 3, kb = ln & 7;
  gload_lds16(grow0 + (size_t)rr * ld + kcol0 + ((kb ^ rr) << 3), lds_u);
}

#define LDA_FRAGS(mh, buf)                                                         \
  _Pragma("unroll") for (int mf = 0; mf < 4; ++mf)                                 \
  _Pragma("unroll") for (int kk = 0; kk < 2; ++kk)                                 \
    av[mf][kk] = *(const bf16x8*)(LA + (buf) * 16384 +                             \
        (wm * 128 + (mh) * 64 + mf * 16 + lr) * 64 + (((kk * 4 + lq) ^ key) << 3));

#define LDB_FRAGS(nh, buf)                                                         \
  _Pragma("unroll") for (int nf = 0; nf < 2; ++nf)                                 \
  _Pragma("unroll") for (int kk = 0; kk < 2; ++kk)                                 \
    bb[nh][nf][kk] = *(const bf16x8*)(LB + (buf) * 16384 +                         \
        (wn * 64 + (nh) * 32 + nf * 16 + lr) * 64 + (((kk * 4 + lq) ^ key) << 3));

#define MFMA_Q(mh, nh)                                                             \
  __builtin_amdgcn_s_setprio(1);                                                   \
  _Pragma("unroll") for (int mf = 0; mf < 4; ++mf)                                 \
  _Pragma("unroll") for (int nf = 0; nf < 2; ++nf)                                 \
  _Pragma("unroll") for (int kk = 0; kk < 2; ++kk)                                 \
    acc[(mh) * 4 + mf][(nh) * 2 + nf] = __builtin_amdgcn_mfma_f32_16x16x32_bf16(   \
        av[mf][kk], bb[nh][nf][kk], acc[(mh) * 4 + mf][(nh) * 2 + nf], 0, 0, 0);   \
  __builtin_amdgcn_s_setprio(0);

#define STAGE_A(unit, kt, buf)                                                     \
  _Pragma("unroll") for (int c = 0; c < 2; ++c) {                                  \
    int g = w * 2 + c;                                                             \
    int r0 = ((g < 8) ? g * 8 : (g - 8) * 8 + 128) + (unit) * 64;                  \
    stage8(Ag + (size_t)r0 * ldK, ldK, (kt) * 64, LA + (buf) * 16384 + r0 * 64, ln); \
  }

#define STAGE_B(half, kt, buf)                                                     \
  _Pragma("unroll") for (int c = 0; c < 2; ++c) {                                  \
    int g = w * 2 + c;                                                             \
    int r0 = (g >> 2) * 64 + (half) * 32 + (g & 3) * 8;                            \
    stage8(Bg + (size_t)r0 * ldK, ldK, (kt) * 64, LB + (buf) * 16384 + r0 * 64, ln); \
  }

__global__ __launch_bounds__(512, 2) void gemm8p_sk(const u16* __restrict__ A,
                                                    const u16* __restrict__ Bt,
                                                    float* __restrict__ C0,
                                                    float* __restrict__ C1,
                                                    int M, int N, int Ks, int ldK) {
  __shared__ alignas(16) u16 lds[65536];
  u16* LA = lds;
  u16* LB = lds + 32768;
  int t = threadIdx.x;
  int w = t >> 6, ln = t & 63;
  int wm = w >> 2, wn = w & 3;
  int bn, bm;
  swz_block(gridDim.x, bn, bm);
  int lr = ln & 15, lq = ln >> 4, key = ln & 7;
  int NT = Ks >> 6;
  int kz = blockIdx.z * Ks;
  const u16* Ag = A + (size_t)bm * 256 * ldK + kz;
  const u16* Bg = Bt + (size_t)bn * 256 * ldK + kz;
  f32x4 acc[8][4] = {};
  bf16x8 av[4][2], bb[2][2][2];

  STAGE_A(0, 0, 0); STAGE_B(0, 0, 0); STAGE_B(1, 0, 0); STAGE_A(1, 0, 0);
  int k1 = NT > 1 ? 1 : 0;
  STAGE_A(0, k1, 1); STAGE_B(0, k1, 1); STAGE_B(1, k1, 1);
  asm volatile("s_waitcnt vmcnt(6)" ::: "memory");
  __builtin_amdgcn_s_barrier();

  for (int T = 0; T < NT; ++T) {
    int b0 = T & 1, b1 = b0 ^ 1;
    int kt1 = (T + 1 < NT) ? T + 1 : NT - 1;
    int kt2 = (T + 2 < NT) ? T + 2 : NT - 1;
    LDA_FRAGS(0, b0);
    LDB_FRAGS(0, b0);
    STAGE_A(1, kt1, b1);
    __builtin_amdgcn_s_barrier();
    asm volatile("s_waitcnt lgkmcnt(0)" ::: "memory");
    MFMA_Q(0, 0);
    __builtin_amdgcn_s_barrier();
    LDB_FRAGS(1, b0);
    STAGE_A(0, kt2, b0);
    __builtin_amdgcn_s_barrier();
    asm volatile("s_waitcnt lgkmcnt(0)" ::: "memory");
    MFMA_Q(0, 1);
    __builtin_amdgcn_s_barrier();
    LDA_FRAGS(1, b0);
    STAGE_B(0, kt2, b0);
    __builtin_amdgcn_s_barrier();
    asm volatile("s_waitcnt lgkmcnt(0)" ::: "memory");
    MFMA_Q(1, 1);
    __builtin_amdgcn_s_barrier();
    STAGE_B(1, kt2, b0);
    asm volatile("s_waitcnt vmcnt(6)" ::: "memory");
    __builtin_amdgcn_s_barrier();
    MFMA_Q(1, 0);
    __builtin_amdgcn_s_barrier();
  }

  float* Cpart = blockIdx.z ? C1 : C0;
  int crow0 = bm * 256 + wm * 128;
  int ccol0 = bn * 256 + wn * 64;
#pragma unroll
  for (int mf = 0; mf < 8; ++mf)
#pragma unroll
    for (int nf = 0; nf < 4; ++nf)
#pragma unroll
      for (int r = 0; r < 4; ++r) {
        int row = crow0 + mf * 16 + lq * 4 + r;
        int col = ccol0 + nf * 16 + lr;
        Cpart[(size_t)row * N + col] = acc[mf][nf][r];
      }
}

// ---------------- reduce split-K partials + residual -> out f32 ----------------
__global__ __launch_bounds__(256) void reduce2(const float* __restrict__ p0,
                                               const float* __restrict__ p1,
                                               const float* __restrict__ x,
                                               float* __restrict__ out) {
  int i = blockIdx.x * 256 + threadIdx.x;
  float4 a = ((const float4*)p0)[i];
  float4 b = ((const float4*)p1)[i];
  float4 c = ((const float4*)x)[i];
  ((float4*)out)[i] = make_float4(a.x + b.x + c.x, a.y + b.y + c.y,
                                  a.z + b.z + c.z, a.w + b.w + c.w);
}

// ---------------- 128x128 bf16 GEMM (small shapes) ----------------
// EPI: 0 none, 3 softplus(v + aux[col]); SPLITK: partials at z*M*N
template <int OUT_BF16, int EPI, int SPLITK>
__global__ __launch_bounds__(256) void gemm_bt(const u16* __restrict__ A,
                                               const u16* __restrict__ Bt,
                                               void* __restrict__ Cout,
                                               const float* __restrict__ aux,
                                               int M, int N, int K, int ld, int cthresh) {
  __shared__ alignas(16) u16 As[128 * 32];
  __shared__ alignas(16) u16 Bs[128 * 32];
  int t = threadIdx.x;
  int w = t >> 6, ln = t & 63;
  int wr = w >> 1, wc = w & 1;
  int bm = blockIdx.y, bn = blockIdx.x;
  int lr = ln & 15, lk = (ln >> 4) * 8;
  f32x4 acc[4][4] = {};
  int kz = SPLITK ? blockIdx.z * K : 0;
  const u16* Abase = A + (size_t)bm * 128 * ld + kz;
  const u16* Bbase = Bt + (size_t)bn * 128 * ld + kz;
  for (int k0 = 0; k0 < K; k0 += 32) {
#pragma unroll
    for (int c = 0; c < 2; ++c) {
      int chunk = w * 2 + c;
      int ee = chunk * 512 + ln * 8;
      int row = ee >> 5, col = ee & 31;
      gload_lds16(Abase + (size_t)row * ld + k0 + col, As + chunk * 512);
      gload_lds16(Bbase + (size_t)row * ld + k0 + col, Bs + chunk * 512);
    }
    __syncthreads();
    bf16x8 af[4], bfr[4];
#pragma unroll
    for (int m = 0; m < 4; ++m)
      af[m] = *(const bf16x8*)(As + (wr * 64 + m * 16 + lr) * 32 + lk);
#pragma unroll
    for (int n = 0; n < 4; ++n)
      bfr[n] = *(const bf16x8*)(Bs + (wc * 64 + n * 16 + lr) * 32 + lk);
#pragma unroll
    for (int m = 0; m < 4; ++m)
#pragma unroll
      for (int n = 0; n < 4; ++n)
        acc[m][n] = __builtin_amdgcn_mfma_f32_16x16x32_bf16(af[m], bfr[n], acc[m][n], 0, 0, 0);
    __syncthreads();
  }
  int rb = bm * 128 + wr * 64 + (ln >> 4) * 4;
  int cb = bn * 128 + wc * 64 + lr;
  float* Cpart = SPLITK ? ((float*)Cout + (size_t)blockIdx.z * M * N) : (float*)Cout;
#pragma unroll
  for (int m = 0; m < 4; ++m)
#pragma unroll
    for (int n = 0; n < 4; ++n)
#pragma unroll
      for (int r = 0; r < 4; ++r) {
        int row = rb + m * 16 + r;
        int col = cb + n * 16;
        float v = acc[m][n][r];
        if (EPI == 3) {
          float dtr = v + aux[col];
          v = dtr > 15.f ? dtr : __logf(1.f + __expf(dtr));
        }
        if (OUT_BF16)
          ((u16*)Cpart)[(size_t)row * N + col] = f2bf(v);
        else
          Cpart[(size_t)row * N + col] = v;
      }
}

// ---------------- reduce split-K partials -> xdbl f32, side-write dt_low bf16 ----------------
__global__ __launch_bounds__(256) void reduce_xdbl(const float* __restrict__ part,
                                                   float* __restrict__ xdbl,
                                                   u16* __restrict__ dtlow) {
  int i = blockIdx.x * 256 + threadIdx.x;
  float s = 0.f;
#pragma unroll
  for (int z = 0; z < 8; ++z) s += part[(size_t)z * (8192 * 128) + i];
  xdbl[i] = s;
  int col = i & 127;
  if (col < 64) dtlow[(size_t)(i >> 7) * 64 + col] = f2bf(s);
}

// ---------------- depthwise causal conv(4) + SiLU ----------------
__global__ __launch_bounds__(256) void conv_silu(const u16* __restrict__ xz,
                                                 const float* __restrict__ cw,
                                                 const float* __restrict__ cb,
                                                 u16* __restrict__ out) {
  int d = blockIdx.x * 256 + threadIdx.x;
  int l0 = blockIdx.y * 8;
  int b = blockIdx.z;
  float w0 = cw[d * 4 + 0], w1 = cw[d * 4 + 1], w2 = cw[d * 4 + 2], w3 = cw[d * 4 + 3];
  float bias = cb[d];
  const u16* xp = xz + ((size_t)b * LSEQ) * 4096 + d;
  float xv[11];
#pragma unroll
  for (int i = 0; i < 11; ++i) {
    int l = l0 - 3 + i;
    xv[i] = (l >= 0) ? bf2f(xp[(size_t)l * 4096]) : 0.f;
  }
  u16* op = out + ((size_t)b * LSEQ + l0) * DINNER + d;
#pragma unroll
  for (int i = 0; i < 8; ++i) {
    float acc = bias + w0 * xv[i] + w1 * xv[i + 1] + w2 * xv[i + 2] + w3 * xv[i + 3];
    float sv = acc * sigmoidf_(acc);
    op[(size_t)i * DINNER] = f2bf(sv);
  }
}

// ---- compute a[16] = exp(dt*An[n]); fast path when An = -(n+1) (uniform branch) ----
__device__ __forceinline__ void compute_a(float dt, const float* An, bool fast, float* av) {
  if (fast) {
    float q = __expf(-dt);
    float q2 = q * q, q4 = q2 * q2;
    av[0] = q; av[1] = q2; av[2] = q2 * q; av[3] = q4;
#pragma unroll
    for (int n = 4; n < 16; ++n) av[n] = av[n - 4] * q4;
  } else {
#pragma unroll
    for (int n = 0; n < 16; ++n) av[n] = __expf(dt * An[n]);
  }
}

// ---------------- scan pass 1 ----------------
__global__ __launch_bounds__(256) void scan1(const u16* __restrict__ dtbf,
                                             const u16* __restrict__ ubf,
                                             const float* __restrict__ xdbl,
                                             const float* __restrict__ A_log,
                                             float* __restrict__ P,
                                             float* __restrict__ H) {
  int d = blockIdx.x * 256 + threadIdx.x;
  int b = blockIdx.y, c = blockIdx.z;
  size_t row0 = (size_t)b * LSEQ + c * 64;
  float An[16];
  bool fast = true;
  {
    const float4* A4 = (const float4*)(A_log + (size_t)d * 16);
#pragma unroll
    for (int q = 0; q < 4; ++q) {
      float4 a = A4[q];
      An[q * 4 + 0] = -__expf(a.x);
      An[q * 4 + 1] = -__expf(a.y);
      An[q * 4 + 2] = -__expf(a.z);
      An[q * 4 + 3] = -__expf(a.w);
    }
#pragma unroll
    for (int n = 0; n < 16; ++n)
      fast = fast && (__builtin_fabsf(An[n] + (float)(n + 1)) < 1e-3f * (n + 1));
  }
  const u16* dtp = dtbf + row0 * DINNER + d;
  const u16* up = ubf + row0 * DINNER + d;
  const float* Bp = xdbl + row0 * 128 + 64;
  float h[16];
#pragma unroll
  for (int n = 0; n < 16; ++n) h[n] = 0.f;
  float sdt = 0.f;
#pragma unroll 2
  for (int i = 0; i < 64; ++i) {
    float dt = bf2f(dtp[(size_t)i * DINNER]);
    float uu = bf2f(up[(size_t)i * DINNER]);
    float dtu = dt * uu;
    sdt += dt;
    const float4* B4 = (const float4*)(Bp + (size_t)i * 128);
    float4 b0 = B4[0], b1 = B4[1], b2 = B4[2], b3 = B4[3];
    float Bf[16] = {b0.x, b0.y, b0.z, b0.w, b1.x, b1.y, b1.z, b1.w,
                    b2.x, b2.y, b2.z, b2.w, b3.x, b3.y, b3.z, b3.w};
    float av[16];
    compute_a(dt, An, fast, av);
#pragma unroll
    for (int n = 0; n < 16; ++n) h[n] = av[n] * h[n] + dtu * Bf[n];
  }
  size_t idx = (size_t)c * 65536 + ((size_t)b * DINNER + d) * 16;
  float4* P4 = (float4*)(P + idx);
  float4* H4 = (float4*)(H + idx);
#pragma unroll
  for (int q = 0; q < 4; ++q) {
    P4[q] = make_float4(__expf(An[q * 4 + 0] * sdt), __expf(An[q * 4 + 1] * sdt),
                        __expf(An[q * 4 + 2] * sdt), __expf(An[q * 4 + 3] * sdt));
    H4[q] = make_float4(h[q * 4], h[q * 4 + 1], h[q * 4 + 2], h[q * 4 + 3]);
  }
}

// ---------------- scan pass 2 ----------------
__global__ __launch_bounds__(256) void scan2(const float* __restrict__ P,
                                             const float* __restrict__ H,
                                             float* __restrict__ Hinit) {
  int i = blockIdx.x * 256 + threadIdx.x;
  float h = 0.f;
  for (int c = 0; c < 64; ++c) {
    Hinit[(size_t)c * 65536 + i] = h;
    h = P[(size_t)c * 65536 + i] * h + H[(size_t)c * 65536 + i];
  }
}

// ---------------- scan pass 3 ----------------
__global__ __launch_bounds__(256) void scan3(const u16* __restrict__ dtbf,
                                             const u16* __restrict__ ubf,
                                             const float* __restrict__ xdbl,
                                             const float* __restrict__ A_log,
                                             const float* __restrict__ Dp,
                                             const u16* __restrict__ xzbf,
                                             const float* __restrict__ Hinit,
                                             u16* __restrict__ ybf) {
  int d = blockIdx.x * 256 + threadIdx.x;
  int b = blockIdx.y, c = blockIdx.z;
  size_t row0 = (size_t)b * LSEQ + c * 64;
  float An[16];
  bool fast = true;
  {
    const float4* A4 = (const float4*)(A_log + (size_t)d * 16);
#pragma unroll
    for (int q = 0; q < 4; ++q) {
      float4 a = A4[q];
      An[q * 4 + 0] = -__expf(a.x);
      An[q * 4 + 1] = -__expf(a.y);
      An[q * 4 + 2] = -__expf(a.z);
      An[q * 4 + 3] = -__expf(a.w);
    }
#pragma unroll
    for (int n = 0; n < 16; ++n)
      fast = fast && (__builtin_fabsf(An[n] + (float)(n + 1)) < 1e-3f * (n + 1));
  }
  const u16* dtp = dtbf + row0 * DINNER + d;
  const u16* up = ubf + row0 * DINNER + d;
  const float* Bp = xdbl + row0 * 128 + 64;
  const float* Cp = xdbl + row0 * 128 + 80;
  const u16* gp = xzbf + row0 * 4096 + DINNER + d;
  u16* yp = ybf + row0 * DINNER + d;
  float Dv = Dp[d];
  float h[16];
  {
    const float4* Hi4 = (const float4*)(Hinit + (size_t)c * 65536 + ((size_t)b * DINNER + d) * 16);
#pragma unroll
    for (int q = 0; q < 4; ++q) {
      float4 hv = Hi4[q];
      h[q * 4 + 0] = hv.x; h[q * 4 + 1] = hv.y; h[q * 4 + 2] = hv.z; h[q * 4 + 3] = hv.w;
    }
  }
#pragma unroll 2
  for (int i = 0; i < 64; ++i) {
    float dt = bf2f(dtp[(size_t)i * DINNER]);
    float uu = bf2f(up[(size_t)i * DINNER]);
    float dtu = dt * uu;
    const float4* B4 = (const float4*)(Bp + (size_t)i * 128);
    float4 b0 = B4[0], b1 = B4[1], b2 = B4[2], b3 = B4[3];
    float Bf[16] = {b0.x, b0.y, b0.z, b0.w, b1.x, b1.y, b1.z, b1.w,
                    b2.x, b2.y, b2.z, b2.w, b3.x, b3.y, b3.z, b3.w};
    const float4* C4 = (const float4*)(Cp + (size_t)i * 128);
    float4 c0 = C4[0], c1 = C4[1], c2 = C4[2], c3 = C4[3];
    float Cf[16] = {c0.x, c0.y, c0.z, c0.w, c1.x, c1.y, c1.z, c1.w,
                    c2.x, c2.y, c2.z, c2.w, c3.x, c3.y, c3.z, c3.w};
    float av[16];
    compute_a(dt, An, fast, av);
    float y = 0.f;
#pragma unroll
    for (int n = 0; n < 16; ++n) {
      h[n] = av[n] * h[n] + dtu * Bf[n];
      y += h[n] * Cf[n];
    }
    float g = bf2f(gp[(size_t)i * 4096]);
    yp[(size_t)i * DINNER] = f2bf((y + uu * Dv) * g);
  }
}

extern "C" void kernel_launch(void* const* d_in, const int* in_sizes, int n_in,
                              void* d_out, int out_size, void* d_ws, size_t ws_size,
                              hipStream_t stream) {
  const float* x = (const float*)d_in[0];
  const float* nw = (const float*)d_in[1];
  const float* nb = (const float*)d_in[2];
  const float* W_in = (const float*)d_in[3];
  const float* convw = (const float*)d_in[4];
  const float* convb = (const float*)d_in[5];
  const float* W_x = (const float*)d_in[6];
  const float* W_dt = (const float*)d_in[7];
  const float* b_dt = (const float*)d_in[8];
  const float* A_log = (const float*)d_in[9];
  const float* Dp = (const float*)d_in[10];
  const float* W_out = (const float*)d_in[11];
  float* out = (float*)d_out;

  char* wp = (char*)d_ws;
  auto alloc = [&](size_t bytes) {
    char* p = wp;
    wp += (bytes + 255) & ~(size_t)255;
    return p;
  };
  u16* xz_bf = (u16*)alloc((size_t)8192 * 4096 * 2);     // x half raw, z half silu'd
  u16* xconv_bf = (u16*)alloc((size_t)8192 * 2048 * 2);  // u
  u16* xn_bf = (u16*)alloc((size_t)8192 * 1024 * 2);
  float* xdbl = (float*)alloc((size_t)8192 * 128 * 4);
  u16* dt_bf = (u16*)alloc((size_t)8192 * 2048 * 2);     // softplus'd dt
  u16* dtlow_bf = (u16*)alloc((size_t)8192 * 64 * 2);
  u16* Wint = (u16*)alloc((size_t)4096 * 1024 * 2);
  u16* Wxt = (u16*)alloc((size_t)128 * 2048 * 2);
  u16* Wdtt = (u16*)alloc((size_t)2048 * 64 * 2);
  u16* Woutt = (u16*)alloc((size_t)1024 * 2048 * 2);
  float* P = (float*)alloc((size_t)64 * 65536 * 4);
  float* H = (float*)alloc((size_t)64 * 65536 * 4);
  float* Hinit = (float*)alloc((size_t)64 * 65536 * 4);
  // overlays:
  float* xdbl_part = (float*)P;      // split-K partials for W_x gemm, dead before scan1
  u16* y_bf = (u16*)P;               // scan3 output over P+H (P,H dead after scan2)
  float* gpart0 = (float*)dt_bf;     // GEMM4 split-K partials: dt_bf dead after scan3
  float* gpart1 = (float*)xconv_bf;  // xconv dead after scan3 (both 33.5MB = 8192*1024*4)

  // weight prep (B^T bf16)
  tc_kernel<<<dim3(128, 32), 256, 0, stream>>>(W_in, Wint, 1024, 4096, 4096);
  tc_kernel<<<dim3(4, 64), 256, 0, stream>>>(W_x, Wxt, 2048, 96, 128);
  tc_kernel<<<dim3(64, 2), 256, 0, stream>>>(W_dt, Wdtt, 64, 2048, 2048);
  tc_kernel<<<dim3(32, 64), 256, 0, stream>>>(W_out, Woutt, 2048, 1024, 1024);

  ln_kernel<<<8192, 256, 0, stream>>>(x, nw, nb, xn_bf);
  // xz = xn @ W_in, z-half silu'd in epilogue  (BK=32, 2 blocks/CU)
  gemm32<1, 2><<<dim3(16, 32), 512, 0, stream>>>(xn_bf, Wint, xz_bf, 8192, 4096, 1024, 2048);
  conv_silu<<<dim3(8, 512, 2), 256, 0, stream>>>(xz_bf, convw, convb, xconv_bf);
  // x_dbl = x_conv @ W_x : split-K x8 partials, then reduce (+ dt_low bf16 side-write)
  gemm_bt<0, 0, 1><<<dim3(1, 64, 8), 256, 0, stream>>>(xconv_bf, Wxt, xdbl_part, nullptr,
                                                       8192, 128, 256, 2048, 0);
  reduce_xdbl<<<4096, 256, 0, stream>>>(xdbl_part, xdbl, dtlow_bf);
  // dt = softplus(dt_low @ W_dt + b_dt)
  gemm_bt<1, 3, 0><<<dim3(16, 64), 256, 0, stream>>>(dtlow_bf, Wdtt, dt_bf, b_dt,
                                                     8192, 2048, 64, 64, 0);
  scan1<<<dim3(8, 2, 64), 256, 0, stream>>>(dt_bf, xconv_bf, xdbl, A_log, P, H);
  scan2<<<256, 256, 0, stream>>>(P, H, Hinit);
  scan3<<<dim3(8, 2, 64), 256, 0, stream>>>(dt_bf, xconv_bf, xdbl, A_log, Dp, xz_bf,
                                            Hinit, y_bf);
  // y @ W_out : split-K x2 (full machine), then reduce + residual
  gemm8p_sk<<<dim3(4, 32, 2), 512, 0, stream>>>(y_bf, Woutt, gpart0, gpart1,
                                                8192, 1024, 1024, 2048);
  reduce2<<<8192, 256, 0, stream>>>(gpart0, gpart1, x, out);
}

// Round 6
// 331.031 us; speedup vs baseline: 2.7748x; 2.7748x over previous
//
#include <hip/hip_runtime.h>

typedef unsigned short u16;
typedef __attribute__((ext_vector_type(8))) __bf16 bf16x8;
typedef __attribute__((ext_vector_type(4))) float f32x4;

#define LSEQ 4096
#define DMODEL 1024
#define DINNER 2048

__device__ __forceinline__ float bf2f(u16 u) {
  union { unsigned u; float f; } v; v.u = ((unsigned)u) << 16; return v.f;
}
__device__ __forceinline__ u16 f2bf(float f) {
  union { float f; unsigned u; } v; v.f = f;
  unsigned r = v.u + 0x7fffu + ((v.u >> 16) & 1u);
  return (u16)(r >> 16);
}
__device__ __forceinline__ void gload_lds16(const void* g, void* l) {
  __builtin_amdgcn_global_load_lds(
      (__attribute__((address_space(1))) void*)(unsigned long long)g,
      (__attribute__((address_space(3))) void*)(unsigned int)(unsigned long long)l,
      16, 0, 0);
}
__device__ __forceinline__ float sigmoidf_(float v) { return 1.f / (1.f + __expf(-v)); }

// bijective XCD swizzle (nwg % 8 == 0): XCD x gets contiguous swz chunk -> shared A panels
__device__ __forceinline__ void swz_block(int gx, int& bn, int& bm) {
  int lin = blockIdx.x + gridDim.x * blockIdx.y;
  int q = (gridDim.x * gridDim.y) >> 3;
  int s = (lin & 7) * q + (lin >> 3);
  bn = s % gx;
  bm = s / gx;
}

// ---------------- LayerNorm -> bf16 ----------------
__global__ __launch_bounds__(256) void ln_kernel(const float* __restrict__ x,
                                                 const float* __restrict__ w,
                                                 const float* __restrict__ b,
                                                 u16* __restrict__ out) {
  int row = blockIdx.x;
  const float* xr = x + (size_t)row * DMODEL;
  int t = threadIdx.x;
  float4 v = ((const float4*)xr)[t];
  float s = v.x + v.y + v.z + v.w;
  float s2 = v.x * v.x + v.y * v.y + v.z * v.z + v.w * v.w;
  for (int off = 32; off; off >>= 1) {
    s += __shfl_down(s, off);
    s2 += __shfl_down(s2, off);
  }
  __shared__ float ls[4], ls2[4];
  int wid = t >> 6;
  if ((t & 63) == 0) { ls[wid] = s; ls2[wid] = s2; }
  __syncthreads();
  s = ls[0] + ls[1] + ls[2] + ls[3];
  s2 = ls2[0] + ls2[1] + ls2[2] + ls2[3];
  float mu = s * (1.f / DMODEL);
  float var = s2 * (1.f / DMODEL) - mu * mu;
  float rs = rsqrtf(var + 1e-5f);
  float4 wv = ((const float4*)w)[t];
  float4 bv = ((const float4*)b)[t];
  unsigned p0 = (unsigned)f2bf((v.x - mu) * rs * wv.x + bv.x) |
                ((unsigned)f2bf((v.y - mu) * rs * wv.y + bv.y) << 16);
  unsigned p1 = (unsigned)f2bf((v.z - mu) * rs * wv.z + bv.z) |
                ((unsigned)f2bf((v.w - mu) * rs * wv.w + bv.w) << 16);
  ((uint2*)(out + (size_t)row * DMODEL))[t] = make_uint2(p0, p1);
}

// ---------------- transpose + cast f32[K][N] -> bf16[Npad][K], zero-fill ----------------
__global__ __launch_bounds__(256) void tc_kernel(const float* __restrict__ in,
                                                 u16* __restrict__ out,
                                                 int K, int N, int Npad) {
  __shared__ float tile[32][33];
  int n0 = blockIdx.x * 32, k0 = blockIdx.y * 32;
  int tx = threadIdx.x & 31, ty = threadIdx.x >> 5;
  for (int i = ty; i < 32; i += 8) {
    int k = k0 + i, n = n0 + tx;
    tile[i][tx] = (k < K && n < N) ? in[(size_t)k * N + n] : 0.f;
  }
  __syncthreads();
  for (int i = ty; i < 32; i += 8) {
    int n = n0 + i, k = k0 + tx;
    if (n < Npad && k < K) out[(size_t)n * K + k] = f2bf(tile[tx][i]);
  }
}

// =====================================================================================
// 256x256, BK=64, 128KB LDS, 8-phase (round-4 verified structure), 1 block/CU.
// __launch_bounds__(512,2): 2 waves/EU -> <=256 VGPR/wave (acc 128 + operands fit; do
// NOT raise min-waves — 4 waves/EU caps at 128 VGPR and spills the accumulator).
// LDS: A,B each [2 bufs][256 rows][64 k] bf16, 16B slots swizzled phys = log ^ (row&7);
// staged linearly via global_load_lds with inverse-swizzled per-lane global source.
// One vmcnt(6) per K-tile (3 half-tiles = 6 loads in flight).
// =====================================================================================
__device__ __forceinline__ void stage8(const u16* grow0, int ld, int kcol0,
                                       u16* lds_u, int ln) {
  int rr = ln >> 3, kb = ln & 7;
  gload_lds16(grow0 + (size_t)rr * ld + kcol0 + ((kb ^ rr) << 3), lds_u);
}

#define LDA_FRAGS(mh, buf)                                                         \
  _Pragma("unroll") for (int mf = 0; mf < 4; ++mf)                                 \
  _Pragma("unroll") for (int kk = 0; kk < 2; ++kk)                                 \
    av[mf][kk] = *(const bf16x8*)(LA + (buf) * 16384 +                             \
        (wm * 128 + (mh) * 64 + mf * 16 + lr) * 64 + (((kk * 4 + lq) ^ key) << 3));

#define LDB_FRAGS(nh, buf)                                                         \
  _Pragma("unroll") for (int nf = 0; nf < 2; ++nf)                                 \
  _Pragma("unroll") for (int kk = 0; kk < 2; ++kk)                                 \
    bb[nh][nf][kk] = *(const bf16x8*)(LB + (buf) * 16384 +                         \
        (wn * 64 + (nh) * 32 + nf * 16 + lr) * 64 + (((kk * 4 + lq) ^ key) << 3));

#define MFMA_Q(mh, nh)                                                             \
  __builtin_amdgcn_s_setprio(1);                                                   \
  _Pragma("unroll") for (int mf = 0; mf < 4; ++mf)                                 \
  _Pragma("unroll") for (int nf = 0; nf < 2; ++nf)                                 \
  _Pragma("unroll") for (int kk = 0; kk < 2; ++kk)                                 \
    acc[(mh) * 4 + mf][(nh) * 2 + nf] = __builtin_amdgcn_mfma_f32_16x16x32_bf16(   \
        av[mf][kk], bb[nh][nf][kk], acc[(mh) * 4 + mf][(nh) * 2 + nf], 0, 0, 0);   \
  __builtin_amdgcn_s_setprio(0);

#define STAGE_A(unit, kt, buf)                                                     \
  _Pragma("unroll") for (int c = 0; c < 2; ++c) {                                  \
    int g = w * 2 + c;                                                             \
    int r0 = ((g < 8) ? g * 8 : (g - 8) * 8 + 128) + (unit) * 64;                  \
    stage8(Ag + (size_t)r0 * ldK, ldK, (kt) * 64, LA + (buf) * 16384 + r0 * 64, ln); \
  }

#define STAGE_B(half, kt, buf)                                                     \
  _Pragma("unroll") for (int c = 0; c < 2; ++c) {                                  \
    int g = w * 2 + c;                                                             \
    int r0 = (g >> 2) * 64 + (half) * 32 + (g & 3) * 8;                            \
    stage8(Bg + (size_t)r0 * ldK, ldK, (kt) * 64, LB + (buf) * 16384 + r0 * 64, ln); \
  }

#define GEMM8P_BODY                                                                \
  STAGE_A(0, 0, 0); STAGE_B(0, 0, 0); STAGE_B(1, 0, 0); STAGE_A(1, 0, 0);          \
  int k1 = NT > 1 ? 1 : 0;                                                         \
  STAGE_A(0, k1, 1); STAGE_B(0, k1, 1); STAGE_B(1, k1, 1);                         \
  asm volatile("s_waitcnt vmcnt(6)" ::: "memory");                                 \
  __builtin_amdgcn_s_barrier();                                                    \
  for (int T = 0; T < NT; ++T) {                                                   \
    int b0 = T & 1, b1 = b0 ^ 1;                                                   \
    int kt1 = (T + 1 < NT) ? T + 1 : NT - 1;                                       \
    int kt2 = (T + 2 < NT) ? T + 2 : NT - 1;                                       \
    LDA_FRAGS(0, b0);                                                              \
    LDB_FRAGS(0, b0);                                                              \
    STAGE_A(1, kt1, b1);                                                           \
    __builtin_amdgcn_s_barrier();                                                  \
    asm volatile("s_waitcnt lgkmcnt(0)" ::: "memory");                             \
    MFMA_Q(0, 0);                                                                  \
    __builtin_amdgcn_s_barrier();                                                  \
    LDB_FRAGS(1, b0);                                                              \
    STAGE_A(0, kt2, b0);                                                           \
    __builtin_amdgcn_s_barrier();                                                  \
    asm volatile("s_waitcnt lgkmcnt(0)" ::: "memory");                             \
    MFMA_Q(0, 1);                                                                  \
    __builtin_amdgcn_s_barrier();                                                  \
    LDA_FRAGS(1, b0);                                                              \
    STAGE_B(0, kt2, b0);                                                           \
    __builtin_amdgcn_s_barrier();                                                  \
    asm volatile("s_waitcnt lgkmcnt(0)" ::: "memory");                             \
    MFMA_Q(1, 1);                                                                  \
    __builtin_amdgcn_s_barrier();                                                  \
    STAGE_B(1, kt2, b0);                                                           \
    asm volatile("s_waitcnt vmcnt(6)" ::: "memory");                               \
    __builtin_amdgcn_s_barrier();                                                  \
    MFMA_Q(1, 0);                                                                  \
    __builtin_amdgcn_s_barrier();                                                  \
  }

template <int OUT_BF16, int EPI>  // EPI: 1 = +aux residual (f32), 2 = silu col>=cthresh
__global__ __launch_bounds__(512, 2) void gemm8p(const u16* __restrict__ A,
                                                 const u16* __restrict__ Bt,
                                                 void* __restrict__ Cout,
                                                 const float* __restrict__ aux,
                                                 int M, int N, int K, int cthresh) {
  __shared__ alignas(16) u16 lds[65536];
  u16* LA = lds;
  u16* LB = lds + 32768;
  int t = threadIdx.x;
  int w = t >> 6, ln = t & 63;
  int wm = w >> 2, wn = w & 3;
  int bn, bm;
  swz_block(gridDim.x, bn, bm);
  int lr = ln & 15, lq = ln >> 4, key = ln & 7;
  int ldK = K;
  int NT = K >> 6;
  const u16* Ag = A + (size_t)bm * 256 * ldK;
  const u16* Bg = Bt + (size_t)bn * 256 * ldK;
  f32x4 acc[8][4] = {};
  bf16x8 av[4][2], bb[2][2][2];

  GEMM8P_BODY

  int crow0 = bm * 256 + wm * 128;
  int ccol0 = bn * 256 + wn * 64;
#pragma unroll
  for (int mf = 0; mf < 8; ++mf)
#pragma unroll
    for (int nf = 0; nf < 4; ++nf)
#pragma unroll
      for (int r = 0; r < 4; ++r) {
        int row = crow0 + mf * 16 + lq * 4 + r;
        int col = ccol0 + nf * 16 + lr;
        float v = acc[mf][nf][r];
        if (EPI == 1) v += aux[(size_t)row * N + col];
        if (EPI == 2 && col >= cthresh) v = v * sigmoidf_(v);
        if (OUT_BF16)
          ((u16*)Cout)[(size_t)row * N + col] = f2bf(v);
        else
          ((float*)Cout)[(size_t)row * N + col] = v;
      }
}

// split-K x2 variant: blockIdx.z picks K-half, f32 partials to C0/C1
__global__ __launch_bounds__(512, 2) void gemm8p_sk(const u16* __restrict__ A,
                                                    const u16* __restrict__ Bt,
                                                    float* __restrict__ C0,
                                                    float* __restrict__ C1,
                                                    int M, int N, int Ks, int ldK) {
  __shared__ alignas(16) u16 lds[65536];
  u16* LA = lds;
  u16* LB = lds + 32768;
  int t = threadIdx.x;
  int w = t >> 6, ln = t & 63;
  int wm = w >> 2, wn = w & 3;
  int bn, bm;
  swz_block(gridDim.x, bn, bm);
  int lr = ln & 15, lq = ln >> 4, key = ln & 7;
  int NT = Ks >> 6;
  int kz = blockIdx.z * Ks;
  const u16* Ag = A + (size_t)bm * 256 * ldK + kz;
  const u16* Bg = Bt + (size_t)bn * 256 * ldK + kz;
  f32x4 acc[8][4] = {};
  bf16x8 av[4][2], bb[2][2][2];

  GEMM8P_BODY

  float* Cpart = blockIdx.z ? C1 : C0;
  int crow0 = bm * 256 + wm * 128;
  int ccol0 = bn * 256 + wn * 64;
#pragma unroll
  for (int mf = 0; mf < 8; ++mf)
#pragma unroll
    for (int nf = 0; nf < 4; ++nf)
#pragma unroll
      for (int r = 0; r < 4; ++r) {
        int row = crow0 + mf * 16 + lq * 4 + r;
        int col = ccol0 + nf * 16 + lr;
        Cpart[(size_t)row * N + col] = acc[mf][nf][r];
      }
}

// ---------------- reduce split-K partials + residual -> out f32 ----------------
__global__ __launch_bounds__(256) void reduce2(const float* __restrict__ p0,
                                               const float* __restrict__ p1,
                                               const float* __restrict__ x,
                                               float* __restrict__ out) {
  int i = blockIdx.x * 256 + threadIdx.x;
  float4 a = ((const float4*)p0)[i];
  float4 b = ((const float4*)p1)[i];
  float4 c = ((const float4*)x)[i];
  ((float4*)out)[i] = make_float4(a.x + b.x + c.x, a.y + b.y + c.y,
                                  a.z + b.z + c.z, a.w + b.w + c.w);
}

// ---------------- 128x128 bf16 GEMM (small shapes) ----------------
// EPI: 0 none, 3 softplus(v + aux[col]); SPLITK: partials at z*M*N
template <int OUT_BF16, int EPI, int SPLITK>
__global__ __launch_bounds__(256) void gemm_bt(const u16* __restrict__ A,
                                               const u16* __restrict__ Bt,
                                               void* __restrict__ Cout,
                                               const float* __restrict__ aux,
                                               int M, int N, int K, int ld, int cthresh) {
  __shared__ alignas(16) u16 As[128 * 32];
  __shared__ alignas(16) u16 Bs[128 * 32];
  int t = threadIdx.x;
  int w = t >> 6, ln = t & 63;
  int wr = w >> 1, wc = w & 1;
  int bm = blockIdx.y, bn = blockIdx.x;
  int lr = ln & 15, lk = (ln >> 4) * 8;
  f32x4 acc[4][4] = {};
  int kz = SPLITK ? blockIdx.z * K : 0;
  const u16* Abase = A + (size_t)bm * 128 * ld + kz;
  const u16* Bbase = Bt + (size_t)bn * 128 * ld + kz;
  for (int k0 = 0; k0 < K; k0 += 32) {
#pragma unroll
    for (int c = 0; c < 2; ++c) {
      int chunk = w * 2 + c;
      int ee = chunk * 512 + ln * 8;
      int row = ee >> 5, col = ee & 31;
      gload_lds16(Abase + (size_t)row * ld + k0 + col, As + chunk * 512);
      gload_lds16(Bbase + (size_t)row * ld + k0 + col, Bs + chunk * 512);
    }
    __syncthreads();
    bf16x8 af[4], bfr[4];
#pragma unroll
    for (int m = 0; m < 4; ++m)
      af[m] = *(const bf16x8*)(As + (wr * 64 + m * 16 + lr) * 32 + lk);
#pragma unroll
    for (int n = 0; n < 4; ++n)
      bfr[n] = *(const bf16x8*)(Bs + (wc * 64 + n * 16 + lr) * 32 + lk);
#pragma unroll
    for (int m = 0; m < 4; ++m)
#pragma unroll
      for (int n = 0; n < 4; ++n)
        acc[m][n] = __builtin_amdgcn_mfma_f32_16x16x32_bf16(af[m], bfr[n], acc[m][n], 0, 0, 0);
    __syncthreads();
  }
  int rb = bm * 128 + wr * 64 + (ln >> 4) * 4;
  int cb = bn * 128 + wc * 64 + lr;
  float* Cpart = SPLITK ? ((float*)Cout + (size_t)blockIdx.z * M * N) : (float*)Cout;
#pragma unroll
  for (int m = 0; m < 4; ++m)
#pragma unroll
    for (int n = 0; n < 4; ++n)
#pragma unroll
      for (int r = 0; r < 4; ++r) {
        int row = rb + m * 16 + r;
        int col = cb + n * 16;
        float v = acc[m][n][r];
        if (EPI == 3) {
          float dtr = v + aux[col];
          v = dtr > 15.f ? dtr : __logf(1.f + __expf(dtr));
        }
        if (OUT_BF16)
          ((u16*)Cpart)[(size_t)row * N + col] = f2bf(v);
        else
          Cpart[(size_t)row * N + col] = v;
      }
}

// ---------------- reduce split-K partials -> xdbl f32, side-write dt_low bf16 ----------------
__global__ __launch_bounds__(256) void reduce_xdbl(const float* __restrict__ part,
                                                   float* __restrict__ xdbl,
                                                   u16* __restrict__ dtlow) {
  int i = blockIdx.x * 256 + threadIdx.x;
  float s = 0.f;
#pragma unroll
  for (int z = 0; z < 8; ++z) s += part[(size_t)z * (8192 * 128) + i];
  xdbl[i] = s;
  int col = i & 127;
  if (col < 64) dtlow[(size_t)(i >> 7) * 64 + col] = f2bf(s);
}

// ---------------- depthwise causal conv(4) + SiLU ----------------
__global__ __launch_bounds__(256) void conv_silu(const u16* __restrict__ xz,
                                                 const float* __restrict__ cw,
                                                 const float* __restrict__ cb,
                                                 u16* __restrict__ out) {
  int d = blockIdx.x * 256 + threadIdx.x;
  int l0 = blockIdx.y * 8;
  int b = blockIdx.z;
  float w0 = cw[d * 4 + 0], w1 = cw[d * 4 + 1], w2 = cw[d * 4 + 2], w3 = cw[d * 4 + 3];
  float bias = cb[d];
  const u16* xp = xz + ((size_t)b * LSEQ) * 4096 + d;
  float xv[11];
#pragma unroll
  for (int i = 0; i < 11; ++i) {
    int l = l0 - 3 + i;
    xv[i] = (l >= 0) ? bf2f(xp[(size_t)l * 4096]) : 0.f;
  }
  u16* op = out + ((size_t)b * LSEQ + l0) * DINNER + d;
#pragma unroll
  for (int i = 0; i < 8; ++i) {
    float acc = bias + w0 * xv[i] + w1 * xv[i + 1] + w2 * xv[i + 2] + w3 * xv[i + 3];
    float sv = acc * sigmoidf_(acc);
    op[(size_t)i * DINNER] = f2bf(sv);
  }
}

// ---- compute a[16] = exp(dt*An[n]); fast path when An = -(n+1) (uniform branch) ----
__device__ __forceinline__ void compute_a(float dt, const float* An, bool fast, float* av) {
  if (fast) {
    float q = __expf(-dt);
    float q2 = q * q, q4 = q2 * q2;
    av[0] = q; av[1] = q2; av[2] = q2 * q; av[3] = q4;
#pragma unroll
    for (int n = 4; n < 16; ++n) av[n] = av[n - 4] * q4;
  } else {
#pragma unroll
    for (int n = 0; n < 16; ++n) av[n] = __expf(dt * An[n]);
  }
}

// ---------------- scan pass 1 ----------------
__global__ __launch_bounds__(256) void scan1(const u16* __restrict__ dtbf,
                                             const u16* __restrict__ ubf,
                                             const float* __restrict__ xdbl,
                                             const float* __restrict__ A_log,
                                             float* __restrict__ P,
                                             float* __restrict__ H) {
  int d = blockIdx.x * 256 + threadIdx.x;
  int b = blockIdx.y, c = blockIdx.z;
  size_t row0 = (size_t)b * LSEQ + c * 64;
  float An[16];
  bool fast = true;
  {
    const float4* A4 = (const float4*)(A_log + (size_t)d * 16);
#pragma unroll
    for (int q = 0; q < 4; ++q) {
      float4 a = A4[q];
      An[q * 4 + 0] = -__expf(a.x);
      An[q * 4 + 1] = -__expf(a.y);
      An[q * 4 + 2] = -__expf(a.z);
      An[q * 4 + 3] = -__expf(a.w);
    }
#pragma unroll
    for (int n = 0; n < 16; ++n)
      fast = fast && (__builtin_fabsf(An[n] + (float)(n + 1)) < 1e-3f * (n + 1));
  }
  const u16* dtp = dtbf + row0 * DINNER + d;
  const u16* up = ubf + row0 * DINNER + d;
  const float* Bp = xdbl + row0 * 128 + 64;
  float h[16];
#pragma unroll
  for (int n = 0; n < 16; ++n) h[n] = 0.f;
  float sdt = 0.f;
#pragma unroll 2
  for (int i = 0; i < 64; ++i) {
    float dt = bf2f(dtp[(size_t)i * DINNER]);
    float uu = bf2f(up[(size_t)i * DINNER]);
    float dtu = dt * uu;
    sdt += dt;
    const float4* B4 = (const float4*)(Bp + (size_t)i * 128);
    float4 b0 = B4[0], b1 = B4[1], b2 = B4[2], b3 = B4[3];
    float Bf[16] = {b0.x, b0.y, b0.z, b0.w, b1.x, b1.y, b1.z, b1.w,
                    b2.x, b2.y, b2.z, b2.w, b3.x, b3.y, b3.z, b3.w};
    float av[16];
    compute_a(dt, An, fast, av);
#pragma unroll
    for (int n = 0; n < 16; ++n) h[n] = av[n] * h[n] + dtu * Bf[n];
  }
  size_t idx = (size_t)c * 65536 + ((size_t)b * DINNER + d) * 16;
  float4* P4 = (float4*)(P + idx);
  float4* H4 = (float4*)(H + idx);
#pragma unroll
  for (int q = 0; q < 4; ++q) {
    P4[q] = make_float4(__expf(An[q * 4 + 0] * sdt), __expf(An[q * 4 + 1] * sdt),
                        __expf(An[q * 4 + 2] * sdt), __expf(An[q * 4 + 3] * sdt));
    H4[q] = make_float4(h[q * 4], h[q * 4 + 1], h[q * 4 + 2], h[q * 4 + 3]);
  }
}

// ---------------- scan pass 2 ----------------
__global__ __launch_bounds__(256) void scan2(const float* __restrict__ P,
                                             const float* __restrict__ H,
                                             float* __restrict__ Hinit) {
  int i = blockIdx.x * 256 + threadIdx.x;
  float h = 0.f;
  for (int c = 0; c < 64; ++c) {
    Hinit[(size_t)c * 65536 + i] = h;
    h = P[(size_t)c * 65536 + i] * h + H[(size_t)c * 65536 + i];
  }
}

// ---------------- scan pass 3 ----------------
__global__ __launch_bounds__(256) void scan3(const u16* __restrict__ dtbf,
                                             const u16* __restrict__ ubf,
                                             const float* __restrict__ xdbl,
                                             const float* __restrict__ A_log,
                                             const float* __restrict__ Dp,
                                             const u16* __restrict__ xzbf,
                                             const float* __restrict__ Hinit,
                                             u16* __restrict__ ybf) {
  int d = blockIdx.x * 256 + threadIdx.x;
  int b = blockIdx.y, c = blockIdx.z;
  size_t row0 = (size_t)b * LSEQ + c * 64;
  float An[16];
  bool fast = true;
  {
    const float4* A4 = (const float4*)(A_log + (size_t)d * 16);
#pragma unroll
    for (int q = 0; q < 4; ++q) {
      float4 a = A4[q];
      An[q * 4 + 0] = -__expf(a.x);
      An[q * 4 + 1] = -__expf(a.y);
      An[q * 4 + 2] = -__expf(a.z);
      An[q * 4 + 3] = -__expf(a.w);
    }
#pragma unroll
    for (int n = 0; n < 16; ++n)
      fast = fast && (__builtin_fabsf(An[n] + (float)(n + 1)) < 1e-3f * (n + 1));
  }
  const u16* dtp = dtbf + row0 * DINNER + d;
  const u16* up = ubf + row0 * DINNER + d;
  const float* Bp = xdbl + row0 * 128 + 64;
  const float* Cp = xdbl + row0 * 128 + 80;
  const u16* gp = xzbf + row0 * 4096 + DINNER + d;
  u16* yp = ybf + row0 * DINNER + d;
  float Dv = Dp[d];
  float h[16];
  {
    const float4* Hi4 = (const float4*)(Hinit + (size_t)c * 65536 + ((size_t)b * DINNER + d) * 16);
#pragma unroll
    for (int q = 0; q < 4; ++q) {
      float4 hv = Hi4[q];
      h[q * 4 + 0] = hv.x; h[q * 4 + 1] = hv.y; h[q * 4 + 2] = hv.z; h[q * 4 + 3] = hv.w;
    }
  }
#pragma unroll 2
  for (int i = 0; i < 64; ++i) {
    float dt = bf2f(dtp[(size_t)i * DINNER]);
    float uu = bf2f(up[(size_t)i * DINNER]);
    float dtu = dt * uu;
    const float4* B4 = (const float4*)(Bp + (size_t)i * 128);
    float4 b0 = B4[0], b1 = B4[1], b2 = B4[2], b3 = B4[3];
    float Bf[16] = {b0.x, b0.y, b0.z, b0.w, b1.x, b1.y, b1.z, b1.w,
                    b2.x, b2.y, b2.z, b2.w, b3.x, b3.y, b3.z, b3.w};
    const float4* C4 = (const float4*)(Cp + (size_t)i * 128);
    float4 c0 = C4[0], c1 = C4[1], c2 = C4[2], c3 = C4[3];
    float Cf[16] = {c0.x, c0.y, c0.z, c0.w, c1.x, c1.y, c1.z, c1.w,
                    c2.x, c2.y, c2.z, c2.w, c3.x, c3.y, c3.z, c3.w};
    float av[16];
    compute_a(dt, An, fast, av);
    float y = 0.f;
#pragma unroll
    for (int n = 0; n < 16; ++n) {
      h[n] = av[n] * h[n] + dtu * Bf[n];
      y += h[n] * Cf[n];
    }
    float g = bf2f(gp[(size_t)i * 4096]);
    yp[(size_t)i * DINNER] = f2bf((y + uu * Dv) * g);
  }
}

extern "C" void kernel_launch(void* const* d_in, const int* in_sizes, int n_in,
                              void* d_out, int out_size, void* d_ws, size_t ws_size,
                              hipStream_t stream) {
  const float* x = (const float*)d_in[0];
  const float* nw = (const float*)d_in[1];
  const float* nb = (const float*)d_in[2];
  const float* W_in = (const float*)d_in[3];
  const float* convw = (const float*)d_in[4];
  const float* convb = (const float*)d_in[5];
  const float* W_x = (const float*)d_in[6];
  const float* W_dt = (const float*)d_in[7];
  const float* b_dt = (const float*)d_in[8];
  const float* A_log = (const float*)d_in[9];
  const float* Dp = (const float*)d_in[10];
  const float* W_out = (const float*)d_in[11];
  float* out = (float*)d_out;

  char* wp = (char*)d_ws;
  auto alloc = [&](size_t bytes) {
    char* p = wp;
    wp += (bytes + 255) & ~(size_t)255;
    return p;
  };
  u16* xz_bf = (u16*)alloc((size_t)8192 * 4096 * 2);     // x half raw, z half silu'd
  u16* xconv_bf = (u16*)alloc((size_t)8192 * 2048 * 2);  // u
  u16* xn_bf = (u16*)alloc((size_t)8192 * 1024 * 2);
  float* xdbl = (float*)alloc((size_t)8192 * 128 * 4);
  u16* dt_bf = (u16*)alloc((size_t)8192 * 2048 * 2);     // softplus'd dt
  u16* dtlow_bf = (u16*)alloc((size_t)8192 * 64 * 2);
  u16* Wint = (u16*)alloc((size_t)4096 * 1024 * 2);
  u16* Wxt = (u16*)alloc((size_t)128 * 2048 * 2);
  u16* Wdtt = (u16*)alloc((size_t)2048 * 64 * 2);
  u16* Woutt = (u16*)alloc((size_t)1024 * 2048 * 2);
  float* P = (float*)alloc((size_t)64 * 65536 * 4);
  float* H = (float*)alloc((size_t)64 * 65536 * 4);
  float* Hinit = (float*)alloc((size_t)64 * 65536 * 4);
  // overlays:
  float* xdbl_part = (float*)P;      // split-K partials for W_x gemm, dead before scan1
  u16* y_bf = (u16*)P;               // scan3 output over P+H (P,H dead after scan2)
  float* gpart0 = (float*)dt_bf;     // GEMM4 split-K partials: dt_bf dead after scan3
  float* gpart1 = (float*)xconv_bf;  // xconv dead after scan3 (both 33.5MB = 8192*1024*4)

  // weight prep (B^T bf16)
  tc_kernel<<<dim3(128, 32), 256, 0, stream>>>(W_in, Wint, 1024, 4096, 4096);
  tc_kernel<<<dim3(4, 64), 256, 0, stream>>>(W_x, Wxt, 2048, 96, 128);
  tc_kernel<<<dim3(64, 2), 256, 0, stream>>>(W_dt, Wdtt, 64, 2048, 2048);
  tc_kernel<<<dim3(32, 64), 256, 0, stream>>>(W_out, Woutt, 2048, 1024, 1024);

  ln_kernel<<<8192, 256, 0, stream>>>(x, nw, nb, xn_bf);
  // xz = xn @ W_in, z-half silu'd in epilogue  (256^2 8-phase + XCD swizzle)
  gemm8p<1, 2><<<dim3(16, 32), 512, 0, stream>>>(xn_bf, Wint, xz_bf, nullptr,
                                                 8192, 4096, 1024, 2048);
  conv_silu<<<dim3(8, 512, 2), 256, 0, stream>>>(xz_bf, convw, convb, xconv_bf);
  // x_dbl = x_conv @ W_x : split-K x8 partials, then reduce (+ dt_low bf16 side-write)
  gemm_bt<0, 0, 1><<<dim3(1, 64, 8), 256, 0, stream>>>(xconv_bf, Wxt, xdbl_part, nullptr,
                                                       8192, 128, 256, 2048, 0);
  reduce_xdbl<<<4096, 256, 0, stream>>>(xdbl_part, xdbl, dtlow_bf);
  // dt = softplus(dt_low @ W_dt + b_dt)
  gemm_bt<1, 3, 0><<<dim3(16, 64), 256, 0, stream>>>(dtlow_bf, Wdtt, dt_bf, b_dt,
                                                     8192, 2048, 64, 64, 0);
  scan1<<<dim3(8, 2, 64), 256, 0, stream>>>(dt_bf, xconv_bf, xdbl, A_log, P, H);
  scan2<<<256, 256, 0, stream>>>(P, H, Hinit);
  scan3<<<dim3(8, 2, 64), 256, 0, stream>>>(dt_bf, xconv_bf, xdbl, A_log, Dp, xz_bf,
                                            Hinit, y_bf);
  // y @ W_out : split-K x2 (full machine), then reduce + residual
  gemm8p_sk<<<dim3(4, 32, 2), 512, 0, stream>>>(y_bf, Woutt, gpart0, gpart1,
                                                8192, 1024, 1024, 2048);
  reduce2<<<8192, 256, 0, stream>>>(gpart0, gpart1, x, out);
}

// Round 7
// 317.378 us; speedup vs baseline: 2.8941x; 1.0430x over previous
//
#include <hip/hip_runtime.h>

typedef unsigned short u16;
typedef __attribute__((ext_vector_type(8))) __bf16 bf16x8;
typedef __attribute__((ext_vector_type(4))) float f32x4;

#define LSEQ 4096
#define DMODEL 1024
#define DINNER 2048

__device__ __forceinline__ float bf2f(u16 u) {
  union { unsigned u; float f; } v; v.u = ((unsigned)u) << 16; return v.f;
}
__device__ __forceinline__ u16 f2bf(float f) {
  union { float f; unsigned u; } v; v.f = f;
  unsigned r = v.u + 0x7fffu + ((v.u >> 16) & 1u);
  return (u16)(r >> 16);
}
__device__ __forceinline__ void gload_lds16(const void* g, void* l) {
  __builtin_amdgcn_global_load_lds(
      (__attribute__((address_space(1))) void*)(unsigned long long)g,
      (__attribute__((address_space(3))) void*)(unsigned int)(unsigned long long)l,
      16, 0, 0);
}
__device__ __forceinline__ float sigmoidf_(float v) { return 1.f / (1.f + __expf(-v)); }

// bijective XCD swizzle (nwg % 8 == 0)
__device__ __forceinline__ void swz_block(int gx, int& bn, int& bm) {
  int lin = blockIdx.x + gridDim.x * blockIdx.y;
  int q = (gridDim.x * gridDim.y) >> 3;
  int s = (lin & 7) * q + (lin >> 3);
  bn = s % gx;
  bm = s / gx;
}

// ---------------- LayerNorm -> bf16 ----------------
__global__ __launch_bounds__(256) void ln_kernel(const float* __restrict__ x,
                                                 const float* __restrict__ w,
                                                 const float* __restrict__ b,
                                                 u16* __restrict__ out) {
  int row = blockIdx.x;
  const float* xr = x + (size_t)row * DMODEL;
  int t = threadIdx.x;
  float4 v = ((const float4*)xr)[t];
  float s = v.x + v.y + v.z + v.w;
  float s2 = v.x * v.x + v.y * v.y + v.z * v.z + v.w * v.w;
  for (int off = 32; off; off >>= 1) {
    s += __shfl_down(s, off);
    s2 += __shfl_down(s2, off);
  }
  __shared__ float ls[4], ls2[4];
  int wid = t >> 6;
  if ((t & 63) == 0) { ls[wid] = s; ls2[wid] = s2; }
  __syncthreads();
  s = ls[0] + ls[1] + ls[2] + ls[3];
  s2 = ls2[0] + ls2[1] + ls2[2] + ls2[3];
  float mu = s * (1.f / DMODEL);
  float var = s2 * (1.f / DMODEL) - mu * mu;
  float rs = rsqrtf(var + 1e-5f);
  float4 wv = ((const float4*)w)[t];
  float4 bv = ((const float4*)b)[t];
  unsigned p0 = (unsigned)f2bf((v.x - mu) * rs * wv.x + bv.x) |
                ((unsigned)f2bf((v.y - mu) * rs * wv.y + bv.y) << 16);
  unsigned p1 = (unsigned)f2bf((v.z - mu) * rs * wv.z + bv.z) |
                ((unsigned)f2bf((v.w - mu) * rs * wv.w + bv.w) << 16);
  ((uint2*)(out + (size_t)row * DMODEL))[t] = make_uint2(p0, p1);
}

// ---------------- transpose + cast f32[K][N] -> bf16[Npad][K], zero-fill ----------------
__global__ __launch_bounds__(256) void tc_kernel(const float* __restrict__ in,
                                                 u16* __restrict__ out,
                                                 int K, int N, int Npad) {
  __shared__ float tile[32][33];
  int n0 = blockIdx.x * 32, k0 = blockIdx.y * 32;
  int tx = threadIdx.x & 31, ty = threadIdx.x >> 5;
  for (int i = ty; i < 32; i += 8) {
    int k = k0 + i, n = n0 + tx;
    tile[i][tx] = (k < K && n < N) ? in[(size_t)k * N + n] : 0.f;
  }
  __syncthreads();
  for (int i = ty; i < 32; i += 8) {
    int n = n0 + i, k = k0 + tx;
    if (n < Npad && k < K) out[(size_t)n * K + k] = f2bf(tile[tx][i]);
  }
}

// ---------------- common staging helper: 8 rows x 64k, swizzle key = row&7 ----------------
__device__ __forceinline__ void stage8(const u16* grow0, int ld, int kcol0,
                                       u16* lds_u, int ln) {
  int rr = ln >> 3, kb = ln & 7;
  gload_lds16(grow0 + (size_t)rr * ld + kcol0 + ((kb ^ rr) << 3), lds_u);
}

// =====================================================================================
// gemm8p: 256x256, BK=64, 128KB LDS, 8-phase, 1 block/CU (round-4/6 verified).
// __launch_bounds__(512,2): do NOT raise min-waves (4/EU caps 128 VGPR -> acc spills).
// =====================================================================================
#define LDA_FRAGS(mh, buf)                                                         \
  _Pragma("unroll") for (int mf = 0; mf < 4; ++mf)                                 \
  _Pragma("unroll") for (int kk = 0; kk < 2; ++kk)                                 \
    av[mf][kk] = *(const bf16x8*)(LA + (buf) * 16384 +                             \
        (wm * 128 + (mh) * 64 + mf * 16 + lr) * 64 + (((kk * 4 + lq) ^ key) << 3));

#define LDB_FRAGS(nh, buf)                                                         \
  _Pragma("unroll") for (int nf = 0; nf < 2; ++nf)                                 \
  _Pragma("unroll") for (int kk = 0; kk < 2; ++kk)                                 \
    bb[nh][nf][kk] = *(const bf16x8*)(LB + (buf) * 16384 +                         \
        (wn * 64 + (nh) * 32 + nf * 16 + lr) * 64 + (((kk * 4 + lq) ^ key) << 3));

#define MFMA_Q(mh, nh)                                                             \
  __builtin_amdgcn_s_setprio(1);                                                   \
  _Pragma("unroll") for (int mf = 0; mf < 4; ++mf)                                 \
  _Pragma("unroll") for (int nf = 0; nf < 2; ++nf)                                 \
  _Pragma("unroll") for (int kk = 0; kk < 2; ++kk)                                 \
    acc[(mh) * 4 + mf][(nh) * 2 + nf] = __builtin_amdgcn_mfma_f32_16x16x32_bf16(   \
        av[mf][kk], bb[nh][nf][kk], acc[(mh) * 4 + mf][(nh) * 2 + nf], 0, 0, 0);   \
  __builtin_amdgcn_s_setprio(0);

#define STAGE_A(unit, kt, buf)                                                     \
  _Pragma("unroll") for (int c = 0; c < 2; ++c) {                                  \
    int g = w * 2 + c;                                                             \
    int r0 = ((g < 8) ? g * 8 : (g - 8) * 8 + 128) + (unit) * 64;                  \
    stage8(Ag + (size_t)r0 * ldK, ldK, (kt) * 64, LA + (buf) * 16384 + r0 * 64, ln); \
  }

#define STAGE_B(half, kt, buf)                                                     \
  _Pragma("unroll") for (int c = 0; c < 2; ++c) {                                  \
    int g = w * 2 + c;                                                             \
    int r0 = (g >> 2) * 64 + (half) * 32 + (g & 3) * 8;                            \
    stage8(Bg + (size_t)r0 * ldK, ldK, (kt) * 64, LB + (buf) * 16384 + r0 * 64, ln); \
  }

template <int OUT_BF16, int EPI>  // EPI: 1 = +aux residual (f32), 2 = silu col>=cthresh
__global__ __launch_bounds__(512, 2) void gemm8p(const u16* __restrict__ A,
                                                 const u16* __restrict__ Bt,
                                                 void* __restrict__ Cout,
                                                 const float* __restrict__ aux,
                                                 int M, int N, int K, int cthresh) {
  __shared__ alignas(16) u16 lds[65536];
  u16* LA = lds;
  u16* LB = lds + 32768;
  int t = threadIdx.x;
  int w = t >> 6, ln = t & 63;
  int wm = w >> 2, wn = w & 3;
  int bn, bm;
  swz_block(gridDim.x, bn, bm);
  int lr = ln & 15, lq = ln >> 4, key = ln & 7;
  int ldK = K;
  int NT = K >> 6;
  const u16* Ag = A + (size_t)bm * 256 * ldK;
  const u16* Bg = Bt + (size_t)bn * 256 * ldK;
  f32x4 acc[8][4] = {};
  bf16x8 av[4][2], bb[2][2][2];

  STAGE_A(0, 0, 0); STAGE_B(0, 0, 0); STAGE_B(1, 0, 0); STAGE_A(1, 0, 0);
  int k1 = NT > 1 ? 1 : 0;
  STAGE_A(0, k1, 1); STAGE_B(0, k1, 1); STAGE_B(1, k1, 1);
  asm volatile("s_waitcnt vmcnt(6)" ::: "memory");
  __builtin_amdgcn_s_barrier();

  for (int T = 0; T < NT; ++T) {
    int b0 = T & 1, b1 = b0 ^ 1;
    int kt1 = (T + 1 < NT) ? T + 1 : NT - 1;
    int kt2 = (T + 2 < NT) ? T + 2 : NT - 1;
    LDA_FRAGS(0, b0);
    LDB_FRAGS(0, b0);
    STAGE_A(1, kt1, b1);
    __builtin_amdgcn_s_barrier();
    asm volatile("s_waitcnt lgkmcnt(0)" ::: "memory");
    MFMA_Q(0, 0);
    __builtin_amdgcn_s_barrier();
    LDB_FRAGS(1, b0);
    STAGE_A(0, kt2, b0);
    __builtin_amdgcn_s_barrier();
    asm volatile("s_waitcnt lgkmcnt(0)" ::: "memory");
    MFMA_Q(0, 1);
    __builtin_amdgcn_s_barrier();
    LDA_FRAGS(1, b0);
    STAGE_B(0, kt2, b0);
    __builtin_amdgcn_s_barrier();
    asm volatile("s_waitcnt lgkmcnt(0)" ::: "memory");
    MFMA_Q(1, 1);
    __builtin_amdgcn_s_barrier();
    STAGE_B(1, kt2, b0);
    asm volatile("s_waitcnt vmcnt(6)" ::: "memory");
    __builtin_amdgcn_s_barrier();
    MFMA_Q(1, 0);
    __builtin_amdgcn_s_barrier();
  }

  int crow0 = bm * 256 + wm * 128;
  int ccol0 = bn * 256 + wn * 64;
#pragma unroll
  for (int mf = 0; mf < 8; ++mf)
#pragma unroll
    for (int nf = 0; nf < 4; ++nf)
#pragma unroll
      for (int r = 0; r < 4; ++r) {
        int row = crow0 + mf * 16 + lq * 4 + r;
        int col = ccol0 + nf * 16 + lr;
        float v = acc[mf][nf][r];
        if (EPI == 1) v += aux[(size_t)row * N + col];
        if (EPI == 2 && col >= cthresh) v = v * sigmoidf_(v);
        if (OUT_BF16)
          ((u16*)Cout)[(size_t)row * N + col] = f2bf(v);
        else
          ((float*)Cout)[(size_t)row * N + col] = v;
      }
}

// =====================================================================================
// gemm128_res: BM=128 x BN=256, BK=64, 96KB LDS, 8-phase, residual fused, f32 out.
// Per-wave out 64x64 (acc = 64 VGPR). A-unit(mh) = 64 rows (1 load/thr),
// B-unit(nh) = 128 rows (2 loads/thr) -> 6 loads/thr/K-tile; counted wait vmcnt(5):
// prologue T0(6)+T1-partial(5) -> all-but-5 = T0 done; steady P3 newest 5 = T+2-partial.
// Same WAR discipline as gemm8p: stage unit(T+2)->b0 only after its last read in T.
// =====================================================================================
#define LDA128(mh, buf)                                                            \
  _Pragma("unroll") for (int mf2 = 0; mf2 < 2; ++mf2)                              \
  _Pragma("unroll") for (int kk = 0; kk < 2; ++kk)                                 \
    av[mf2][kk] = *(const bf16x8*)(LA + (buf) * 8192 +                             \
        (wm * 64 + (mh) * 32 + mf2 * 16 + lr) * 64 + (((kk * 4 + lq) ^ key) << 3));

#define LDB128(nh, buf, B_)                                                        \
  _Pragma("unroll") for (int nf2 = 0; nf2 < 2; ++nf2)                              \
  _Pragma("unroll") for (int kk = 0; kk < 2; ++kk)                                 \
    B_[nf2][kk] = *(const bf16x8*)(LB + (buf) * 16384 +                            \
        (wn * 64 + (nh) * 32 + nf2 * 16 + lr) * 64 + (((kk * 4 + lq) ^ key) << 3));

#define MFMA_Q128(mh, nh, B_)                                                      \
  __builtin_amdgcn_s_setprio(1);                                                   \
  _Pragma("unroll") for (int mf2 = 0; mf2 < 2; ++mf2)                              \
  _Pragma("unroll") for (int nf2 = 0; nf2 < 2; ++nf2)                              \
  _Pragma("unroll") for (int kk = 0; kk < 2; ++kk)                                 \
    acc[(mh) * 2 + mf2][(nh) * 2 + nf2] = __builtin_amdgcn_mfma_f32_16x16x32_bf16( \
        av[mf2][kk], B_[nf2][kk], acc[(mh) * 2 + mf2][(nh) * 2 + nf2], 0, 0, 0);   \
  __builtin_amdgcn_s_setprio(0);

#define STAGE_A128(unit, kt, buf)                                                  \
  {                                                                                \
    int r0 = (w >> 2) * 64 + (unit) * 32 + (w & 3) * 8;                            \
    stage8(Ag + (size_t)r0 * ldK, ldK, (kt) * 64, LA + (buf) * 8192 + r0 * 64, ln); \
  }

#define STAGE_B128(half, kt, buf)                                                  \
  _Pragma("unroll") for (int c = 0; c < 2; ++c) {                                  \
    int g = w * 2 + c;                                                             \
    int r0 = (g >> 2) * 64 + (half) * 32 + (g & 3) * 8;                            \
    stage8(Bg + (size_t)r0 * ldK, ldK, (kt) * 64, LB + (buf) * 16384 + r0 * 64, ln); \
  }

__global__ __launch_bounds__(512, 2) void gemm128_res(const u16* __restrict__ A,
                                                      const u16* __restrict__ Bt,
                                                      float* __restrict__ Cout,
                                                      const float* __restrict__ res,
                                                      int M, int N, int K) {
  __shared__ alignas(16) u16 lds[49152];
  u16* LA = lds;
  u16* LB = lds + 16384;
  int t = threadIdx.x;
  int w = t >> 6, ln = t & 63;
  int wm = w >> 2, wn = w & 3;
  int bn, bm;
  swz_block(gridDim.x, bn, bm);
  int lr = ln & 15, lq = ln >> 4, key = ln & 7;
  int ldK = K;
  int NT = K >> 6;
  const u16* Ag = A + (size_t)bm * 128 * ldK;
  const u16* Bg = Bt + (size_t)bn * 256 * ldK;
  f32x4 acc[4][4] = {};
  bf16x8 av[2][2], bbl[2][2], bbh[2][2];

  STAGE_A128(0, 0, 0); STAGE_B128(0, 0, 0); STAGE_B128(1, 0, 0); STAGE_A128(1, 0, 0);
  int k1 = NT > 1 ? 1 : 0;
  STAGE_A128(0, k1, 1); STAGE_B128(0, k1, 1); STAGE_B128(1, k1, 1);
  asm volatile("s_waitcnt vmcnt(5)" ::: "memory");
  __builtin_amdgcn_s_barrier();

  for (int T = 0; T < NT; ++T) {
    int b0 = T & 1, b1 = b0 ^ 1;
    int kt1 = (T + 1 < NT) ? T + 1 : NT - 1;
    int kt2 = (T + 2 < NT) ? T + 2 : NT - 1;
    // P0: Q(0,0)
    LDA128(0, b0);
    LDB128(0, b0, bbl);
    STAGE_A128(1, kt1, b1);
    __builtin_amdgcn_s_barrier();
    asm volatile("s_waitcnt lgkmcnt(0)" ::: "memory");
    MFMA_Q128(0, 0, bbl);
    __builtin_amdgcn_s_barrier();
    // P1: Q(0,1)
    LDB128(1, b0, bbh);
    STAGE_A128(0, kt2, b0);
    __builtin_amdgcn_s_barrier();
    asm volatile("s_waitcnt lgkmcnt(0)" ::: "memory");
    MFMA_Q128(0, 1, bbh);
    __builtin_amdgcn_s_barrier();
    // P2: Q(1,1)
    LDA128(1, b0);
    STAGE_B128(0, kt2, b0);
    __builtin_amdgcn_s_barrier();
    asm volatile("s_waitcnt lgkmcnt(0)" ::: "memory");
    MFMA_Q128(1, 1, bbh);
    __builtin_amdgcn_s_barrier();
    // P3: Q(1,0)
    STAGE_B128(1, kt2, b0);
    asm volatile("s_waitcnt vmcnt(5)" ::: "memory");
    __builtin_amdgcn_s_barrier();
    MFMA_Q128(1, 0, bbl);
    __builtin_amdgcn_s_barrier();
  }

  int crow0 = bm * 128 + wm * 64;
  int ccol0 = bn * 256 + wn * 64;
#pragma unroll
  for (int mf = 0; mf < 4; ++mf)
#pragma unroll
    for (int nf = 0; nf < 4; ++nf)
#pragma unroll
      for (int r = 0; r < 4; ++r) {
        int row = crow0 + mf * 16 + lq * 4 + r;
        int col = ccol0 + nf * 16 + lr;
        Cout[(size_t)row * N + col] = acc[mf][nf][r] + res[(size_t)row * N + col];
      }
}

// ---------------- 128x128 bf16 GEMM (small shapes) ----------------
// EPI: 0 none, 3 softplus(v + aux[col]); SPLITK: partials at z*M*N
template <int OUT_BF16, int EPI, int SPLITK>
__global__ __launch_bounds__(256) void gemm_bt(const u16* __restrict__ A,
                                               const u16* __restrict__ Bt,
                                               void* __restrict__ Cout,
                                               const float* __restrict__ aux,
                                               int M, int N, int K, int ld, int cthresh) {
  __shared__ alignas(16) u16 As[128 * 32];
  __shared__ alignas(16) u16 Bs[128 * 32];
  int t = threadIdx.x;
  int w = t >> 6, ln = t & 63;
  int wr = w >> 1, wc = w & 1;
  int bm = blockIdx.y, bn = blockIdx.x;
  int lr = ln & 15, lk = (ln >> 4) * 8;
  f32x4 acc[4][4] = {};
  int kz = SPLITK ? blockIdx.z * K : 0;
  const u16* Abase = A + (size_t)bm * 128 * ld + kz;
  const u16* Bbase = Bt + (size_t)bn * 128 * ld + kz;
  for (int k0 = 0; k0 < K; k0 += 32) {
#pragma unroll
    for (int c = 0; c < 2; ++c) {
      int chunk = w * 2 + c;
      int ee = chunk * 512 + ln * 8;
      int row = ee >> 5, col = ee & 31;
      gload_lds16(Abase + (size_t)row * ld + k0 + col, As + chunk * 512);
      gload_lds16(Bbase + (size_t)row * ld + k0 + col, Bs + chunk * 512);
    }
    __syncthreads();
    bf16x8 af[4], bfr[4];
#pragma unroll
    for (int m = 0; m < 4; ++m)
      af[m] = *(const bf16x8*)(As + (wr * 64 + m * 16 + lr) * 32 + lk);
#pragma unroll
    for (int n = 0; n < 4; ++n)
      bfr[n] = *(const bf16x8*)(Bs + (wc * 64 + n * 16 + lr) * 32 + lk);
#pragma unroll
    for (int m = 0; m < 4; ++m)
#pragma unroll
      for (int n = 0; n < 4; ++n)
        acc[m][n] = __builtin_amdgcn_mfma_f32_16x16x32_bf16(af[m], bfr[n], acc[m][n], 0, 0, 0);
    __syncthreads();
  }
  int rb = bm * 128 + wr * 64 + (ln >> 4) * 4;
  int cb = bn * 128 + wc * 64 + lr;
  float* Cpart = SPLITK ? ((float*)Cout + (size_t)blockIdx.z * M * N) : (float*)Cout;
#pragma unroll
  for (int m = 0; m < 4; ++m)
#pragma unroll
    for (int n = 0; n < 4; ++n)
#pragma unroll
      for (int r = 0; r < 4; ++r) {
        int row = rb + m * 16 + r;
        int col = cb + n * 16;
        float v = acc[m][n][r];
        if (EPI == 3) {
          float dtr = v + aux[col];
          v = dtr > 15.f ? dtr : __logf(1.f + __expf(dtr));
        }
        if (OUT_BF16)
          ((u16*)Cpart)[(size_t)row * N + col] = f2bf(v);
        else
          Cpart[(size_t)row * N + col] = v;
      }
}

// ---------------- reduce split-K partials -> xdbl f32, side-write dt_low bf16 ----------------
__global__ __launch_bounds__(256) void reduce_xdbl(const float* __restrict__ part,
                                                   float* __restrict__ xdbl,
                                                   u16* __restrict__ dtlow) {
  int i = blockIdx.x * 256 + threadIdx.x;
  float s = 0.f;
#pragma unroll
  for (int z = 0; z < 8; ++z) s += part[(size_t)z * (8192 * 128) + i];
  xdbl[i] = s;
  int col = i & 127;
  if (col < 64) dtlow[(size_t)(i >> 7) * 64 + col] = f2bf(s);
}

// ---------------- depthwise causal conv(4) + SiLU ----------------
__global__ __launch_bounds__(256) void conv_silu(const u16* __restrict__ xz,
                                                 const float* __restrict__ cw,
                                                 const float* __restrict__ cb,
                                                 u16* __restrict__ out) {
  int d = blockIdx.x * 256 + threadIdx.x;
  int l0 = blockIdx.y * 8;
  int b = blockIdx.z;
  float w0 = cw[d * 4 + 0], w1 = cw[d * 4 + 1], w2 = cw[d * 4 + 2], w3 = cw[d * 4 + 3];
  float bias = cb[d];
  const u16* xp = xz + ((size_t)b * LSEQ) * 4096 + d;
  float xv[11];
#pragma unroll
  for (int i = 0; i < 11; ++i) {
    int l = l0 - 3 + i;
    xv[i] = (l >= 0) ? bf2f(xp[(size_t)l * 4096]) : 0.f;
  }
  u16* op = out + ((size_t)b * LSEQ + l0) * DINNER + d;
#pragma unroll
  for (int i = 0; i < 8; ++i) {
    float acc = bias + w0 * xv[i] + w1 * xv[i + 1] + w2 * xv[i + 2] + w3 * xv[i + 3];
    float sv = acc * sigmoidf_(acc);
    op[(size_t)i * DINNER] = f2bf(sv);
  }
}

// ---- compute a[16] = exp(dt*An[n]); fast path when An = -(n+1) (uniform branch) ----
__device__ __forceinline__ void compute_a(float dt, const float* An, bool fast, float* av) {
  if (fast) {
    float q = __expf(-dt);
    float q2 = q * q, q4 = q2 * q2;
    av[0] = q; av[1] = q2; av[2] = q2 * q; av[3] = q4;
#pragma unroll
    for (int n = 4; n < 16; ++n) av[n] = av[n - 4] * q4;
  } else {
#pragma unroll
    for (int n = 0; n < 16; ++n) av[n] = __expf(dt * An[n]);
  }
}

// ---------------- scan pass 1 ----------------
__global__ __launch_bounds__(256) void scan1(const u16* __restrict__ dtbf,
                                             const u16* __restrict__ ubf,
                                             const float* __restrict__ xdbl,
                                             const float* __restrict__ A_log,
                                             float* __restrict__ P,
                                             float* __restrict__ H) {
  int d = blockIdx.x * 256 + threadIdx.x;
  int b = blockIdx.y, c = blockIdx.z;
  size_t row0 = (size_t)b * LSEQ + c * 64;
  float An[16];
  bool fast = true;
  {
    const float4* A4 = (const float4*)(A_log + (size_t)d * 16);
#pragma unroll
    for (int q = 0; q < 4; ++q) {
      float4 a = A4[q];
      An[q * 4 + 0] = -__expf(a.x);
      An[q * 4 + 1] = -__expf(a.y);
      An[q * 4 + 2] = -__expf(a.z);
      An[q * 4 + 3] = -__expf(a.w);
    }
#pragma unroll
    for (int n = 0; n < 16; ++n)
      fast = fast && (__builtin_fabsf(An[n] + (float)(n + 1)) < 1e-3f * (n + 1));
  }
  const u16* dtp = dtbf + row0 * DINNER + d;
  const u16* up = ubf + row0 * DINNER + d;
  const float* Bp = xdbl + row0 * 128 + 64;
  float h[16];
#pragma unroll
  for (int n = 0; n < 16; ++n) h[n] = 0.f;
  float sdt = 0.f;
#pragma unroll 2
  for (int i = 0; i < 64; ++i) {
    float dt = bf2f(dtp[(size_t)i * DINNER]);
    float uu = bf2f(up[(size_t)i * DINNER]);
    float dtu = dt * uu;
    sdt += dt;
    const float4* B4 = (const float4*)(Bp + (size_t)i * 128);
    float4 b0 = B4[0], b1 = B4[1], b2 = B4[2], b3 = B4[3];
    float Bf[16] = {b0.x, b0.y, b0.z, b0.w, b1.x, b1.y, b1.z, b1.w,
                    b2.x, b2.y, b2.z, b2.w, b3.x, b3.y, b3.z, b3.w};
    float av[16];
    compute_a(dt, An, fast, av);
#pragma unroll
    for (int n = 0; n < 16; ++n) h[n] = av[n] * h[n] + dtu * Bf[n];
  }
  size_t idx = (size_t)c * 65536 + ((size_t)b * DINNER + d) * 16;
  float4* P4 = (float4*)(P + idx);
  float4* H4 = (float4*)(H + idx);
#pragma unroll
  for (int q = 0; q < 4; ++q) {
    P4[q] = make_float4(__expf(An[q * 4 + 0] * sdt), __expf(An[q * 4 + 1] * sdt),
                        __expf(An[q * 4 + 2] * sdt), __expf(An[q * 4 + 3] * sdt));
    H4[q] = make_float4(h[q * 4], h[q * 4 + 1], h[q * 4 + 2], h[q * 4 + 3]);
  }
}

// ---------------- scan pass 2 ----------------
__global__ __launch_bounds__(256) void scan2(const float* __restrict__ P,
                                             const float* __restrict__ H,
                                             float* __restrict__ Hinit) {
  int i = blockIdx.x * 256 + threadIdx.x;
  float h = 0.f;
  for (int c = 0; c < 64; ++c) {
    Hinit[(size_t)c * 65536 + i] = h;
    h = P[(size_t)c * 65536 + i] * h + H[(size_t)c * 65536 + i];
  }
}

// ---------------- scan pass 3 ----------------
__global__ __launch_bounds__(256) void scan3(const u16* __restrict__ dtbf,
                                             const u16* __restrict__ ubf,
                                             const float* __restrict__ xdbl,
                                             const float* __restrict__ A_log,
                                             const float* __restrict__ Dp,
                                             const u16* __restrict__ xzbf,
                                             const float* __restrict__ Hinit,
                                             u16* __restrict__ ybf) {
  int d = blockIdx.x * 256 + threadIdx.x;
  int b = blockIdx.y, c = blockIdx.z;
  size_t row0 = (size_t)b * LSEQ + c * 64;
  float An[16];
  bool fast = true;
  {
    const float4* A4 = (const float4*)(A_log + (size_t)d * 16);
#pragma unroll
    for (int q = 0; q < 4; ++q) {
      float4 a = A4[q];
      An[q * 4 + 0] = -__expf(a.x);
      An[q * 4 + 1] = -__expf(a.y);
      An[q * 4 + 2] = -__expf(a.z);
      An[q * 4 + 3] = -__expf(a.w);
    }
#pragma unroll
    for (int n = 0; n < 16; ++n)
      fast = fast && (__builtin_fabsf(An[n] + (float)(n + 1)) < 1e-3f * (n + 1));
  }
  const u16* dtp = dtbf + row0 * DINNER + d;
  const u16* up = ubf + row0 * DINNER + d;
  const float* Bp = xdbl + row0 * 128 + 64;
  const float* Cp = xdbl + row0 * 128 + 80;
  const u16* gp = xzbf + row0 * 4096 + DINNER + d;
  u16* yp = ybf + row0 * DINNER + d;
  float Dv = Dp[d];
  float h[16];
  {
    const float4* Hi4 = (const float4*)(Hinit + (size_t)c * 65536 + ((size_t)b * DINNER + d) * 16);
#pragma unroll
    for (int q = 0; q < 4; ++q) {
      float4 hv = Hi4[q];
      h[q * 4 + 0] = hv.x; h[q * 4 + 1] = hv.y; h[q * 4 + 2] = hv.z; h[q * 4 + 3] = hv.w;
    }
  }
#pragma unroll 2
  for (int i = 0; i < 64; ++i) {
    float dt = bf2f(dtp[(size_t)i * DINNER]);
    float uu = bf2f(up[(size_t)i * DINNER]);
    float dtu = dt * uu;
    const float4* B4 = (const float4*)(Bp + (size_t)i * 128);
    float4 b0 = B4[0], b1 = B4[1], b2 = B4[2], b3 = B4[3];
    float Bf[16] = {b0.x, b0.y, b0.z, b0.w, b1.x, b1.y, b1.z, b1.w,
                    b2.x, b2.y, b2.z, b2.w, b3.x, b3.y, b3.z, b3.w};
    const float4* C4 = (const float4*)(Cp + (size_t)i * 128);
    float4 c0 = C4[0], c1 = C4[1], c2 = C4[2], c3 = C4[3];
    float Cf[16] = {c0.x, c0.y, c0.z, c0.w, c1.x, c1.y, c1.z, c1.w,
                    c2.x, c2.y, c2.z, c2.w, c3.x, c3.y, c3.z, c3.w};
    float av[16];
    compute_a(dt, An, fast, av);
    float y = 0.f;
#pragma unroll
    for (int n = 0; n < 16; ++n) {
      h[n] = av[n] * h[n] + dtu * Bf[n];
      y += h[n] * Cf[n];
    }
    float g = bf2f(gp[(size_t)i * 4096]);
    yp[(size_t)i * DINNER] = f2bf((y + uu * Dv) * g);
  }
}

extern "C" void kernel_launch(void* const* d_in, const int* in_sizes, int n_in,
                              void* d_out, int out_size, void* d_ws, size_t ws_size,
                              hipStream_t stream) {
  const float* x = (const float*)d_in[0];
  const float* nw = (const float*)d_in[1];
  const float* nb = (const float*)d_in[2];
  const float* W_in = (const float*)d_in[3];
  const float* convw = (const float*)d_in[4];
  const float* convb = (const float*)d_in[5];
  const float* W_x = (const float*)d_in[6];
  const float* W_dt = (const float*)d_in[7];
  const float* b_dt = (const float*)d_in[8];
  const float* A_log = (const float*)d_in[9];
  const float* Dp = (const float*)d_in[10];
  const float* W_out = (const float*)d_in[11];
  float* out = (float*)d_out;

  char* wp = (char*)d_ws;
  auto alloc = [&](size_t bytes) {
    char* p = wp;
    wp += (bytes + 255) & ~(size_t)255;
    return p;
  };
  u16* xz_bf = (u16*)alloc((size_t)8192 * 4096 * 2);     // x half raw, z half silu'd
  u16* xconv_bf = (u16*)alloc((size_t)8192 * 2048 * 2);  // u
  u16* xn_bf = (u16*)alloc((size_t)8192 * 1024 * 2);
  float* xdbl = (float*)alloc((size_t)8192 * 128 * 4);
  u16* dt_bf = (u16*)alloc((size_t)8192 * 2048 * 2);     // softplus'd dt
  u16* dtlow_bf = (u16*)alloc((size_t)8192 * 64 * 2);
  u16* Wint = (u16*)alloc((size_t)4096 * 1024 * 2);
  u16* Wxt = (u16*)alloc((size_t)128 * 2048 * 2);
  u16* Wdtt = (u16*)alloc((size_t)2048 * 64 * 2);
  u16* Woutt = (u16*)alloc((size_t)1024 * 2048 * 2);
  float* P = (float*)alloc((size_t)64 * 65536 * 4);
  float* H = (float*)alloc((size_t)64 * 65536 * 4);
  float* Hinit = (float*)alloc((size_t)64 * 65536 * 4);
  // overlays:
  float* xdbl_part = (float*)P;  // split-K partials for W_x gemm, dead before scan1
  u16* y_bf = (u16*)P;           // scan3 output over P+H (P,H dead after scan2)

  // weight prep (B^T bf16)
  tc_kernel<<<dim3(128, 32), 256, 0, stream>>>(W_in, Wint, 1024, 4096, 4096);
  tc_kernel<<<dim3(4, 64), 256, 0, stream>>>(W_x, Wxt, 2048, 96, 128);
  tc_kernel<<<dim3(64, 2), 256, 0, stream>>>(W_dt, Wdtt, 64, 2048, 2048);
  tc_kernel<<<dim3(32, 64), 256, 0, stream>>>(W_out, Woutt, 2048, 1024, 1024);

  ln_kernel<<<8192, 256, 0, stream>>>(x, nw, nb, xn_bf);
  // xz = xn @ W_in, z-half silu'd in epilogue  (256^2 8-phase)
  gemm8p<1, 2><<<dim3(16, 32), 512, 0, stream>>>(xn_bf, Wint, xz_bf, nullptr,
                                                 8192, 4096, 1024, 2048);
  conv_silu<<<dim3(8, 512, 2), 256, 0, stream>>>(xz_bf, convw, convb, xconv_bf);
  // x_dbl = x_conv @ W_x : split-K x8 partials, then reduce (+ dt_low bf16 side-write)
  gemm_bt<0, 0, 1><<<dim3(1, 64, 8), 256, 0, stream>>>(xconv_bf, Wxt, xdbl_part, nullptr,
                                                       8192, 128, 256, 2048, 0);
  reduce_xdbl<<<4096, 256, 0, stream>>>(xdbl_part, xdbl, dtlow_bf);
  // dt = softplus(dt_low @ W_dt + b_dt)
  gemm_bt<1, 3, 0><<<dim3(16, 64), 256, 0, stream>>>(dtlow_bf, Wdtt, dt_bf, b_dt,
                                                     8192, 2048, 64, 64, 0);
  scan1<<<dim3(8, 2, 64), 256, 0, stream>>>(dt_bf, xconv_bf, xdbl, A_log, P, H);
  scan2<<<256, 256, 0, stream>>>(P, H, Hinit);
  scan3<<<dim3(8, 2, 64), 256, 0, stream>>>(dt_bf, xconv_bf, xdbl, A_log, Dp, xz_bf,
                                            Hinit, y_bf);
  // out = residual + y @ W_out  (128x256 tile, full machine in one round, no split-K)
  gemm128_res<<<dim3(4, 64), 512, 0, stream>>>(y_bf, Woutt, out, x, 8192, 1024, 2048);
}

// Round 8
// 313.316 us; speedup vs baseline: 2.9317x; 1.0130x over previous
//
#include <hip/hip_runtime.h>

typedef unsigned short u16;
typedef __attribute__((ext_vector_type(8))) __bf16 bf16x8;
typedef __attribute__((ext_vector_type(4))) float f32x4;

#define LSEQ 4096
#define DMODEL 1024
#define DINNER 2048

__device__ __forceinline__ float bf2f(u16 u) {
  union { unsigned u; float f; } v; v.u = ((unsigned)u) << 16; return v.f;
}
__device__ __forceinline__ u16 f2bf(float f) {
  union { float f; unsigned u; } v; v.f = f;
  unsigned r = v.u + 0x7fffu + ((v.u >> 16) & 1u);
  return (u16)(r >> 16);
}
__device__ __forceinline__ void gload_lds16(const void* g, void* l) {
  __builtin_amdgcn_global_load_lds(
      (__attribute__((address_space(1))) void*)(unsigned long long)g,
      (__attribute__((address_space(3))) void*)(unsigned int)(unsigned long long)l,
      16, 0, 0);
}
__device__ __forceinline__ float sigmoidf_(float v) { return 1.f / (1.f + __expf(-v)); }

// bijective XCD swizzle (nwg % 8 == 0)
__device__ __forceinline__ void swz_block(int gx, int& bn, int& bm) {
  int lin = blockIdx.x + gridDim.x * blockIdx.y;
  int q = (gridDim.x * gridDim.y) >> 3;
  int s = (lin & 7) * q + (lin >> 3);
  bn = s % gx;
  bm = s / gx;
}

// ---------------- LayerNorm -> bf16 ----------------
__global__ __launch_bounds__(256) void ln_kernel(const float* __restrict__ x,
                                                 const float* __restrict__ w,
                                                 const float* __restrict__ b,
                                                 u16* __restrict__ out) {
  int row = blockIdx.x;
  const float* xr = x + (size_t)row * DMODEL;
  int t = threadIdx.x;
  float4 v = ((const float4*)xr)[t];
  float s = v.x + v.y + v.z + v.w;
  float s2 = v.x * v.x + v.y * v.y + v.z * v.z + v.w * v.w;
  for (int off = 32; off; off >>= 1) {
    s += __shfl_down(s, off);
    s2 += __shfl_down(s2, off);
  }
  __shared__ float ls[4], ls2[4];
  int wid = t >> 6;
  if ((t & 63) == 0) { ls[wid] = s; ls2[wid] = s2; }
  __syncthreads();
  s = ls[0] + ls[1] + ls[2] + ls[3];
  s2 = ls2[0] + ls2[1] + ls2[2] + ls2[3];
  float mu = s * (1.f / DMODEL);
  float var = s2 * (1.f / DMODEL) - mu * mu;
  float rs = rsqrtf(var + 1e-5f);
  float4 wv = ((const float4*)w)[t];
  float4 bv = ((const float4*)b)[t];
  unsigned p0 = (unsigned)f2bf((v.x - mu) * rs * wv.x + bv.x) |
                ((unsigned)f2bf((v.y - mu) * rs * wv.y + bv.y) << 16);
  unsigned p1 = (unsigned)f2bf((v.z - mu) * rs * wv.z + bv.z) |
                ((unsigned)f2bf((v.w - mu) * rs * wv.w + bv.w) << 16);
  ((uint2*)(out + (size_t)row * DMODEL))[t] = make_uint2(p0, p1);
}

// ---------------- fused transpose+cast for all 4 weights (one launch) ----------------
// segments: [0,4096) W_in(K1024,N4096), [4096,4352) W_x(K2048,N96,Npad128),
//           [4352,4480) W_dt(K64,N2048), [4480,6528) W_out(K2048,N1024)
__global__ __launch_bounds__(256) void tc_all(const float* __restrict__ W_in,
                                              const float* __restrict__ W_x,
                                              const float* __restrict__ W_dt,
                                              const float* __restrict__ W_out,
                                              u16* __restrict__ o0, u16* __restrict__ o1,
                                              u16* __restrict__ o2, u16* __restrict__ o3) {
  __shared__ float tile[32][33];
  int id = blockIdx.x;
  const float* in;
  u16* out;
  int K, N, Npad, gx, bx;
  if (id < 4096)      { in = W_in;  out = o0; K = 1024; N = 4096; Npad = 4096; gx = 128; bx = id; }
  else if (id < 4352) { in = W_x;   out = o1; K = 2048; N = 96;   Npad = 128;  gx = 4;   bx = id - 4096; }
  else if (id < 4480) { in = W_dt;  out = o2; K = 64;   N = 2048; Npad = 2048; gx = 64;  bx = id - 4352; }
  else                { in = W_out; out = o3; K = 2048; N = 1024; Npad = 1024; gx = 32;  bx = id - 4480; }
  int n0 = (bx % gx) * 32, k0 = (bx / gx) * 32;
  int tx = threadIdx.x & 31, ty = threadIdx.x >> 5;
  for (int i = ty; i < 32; i += 8) {
    int k = k0 + i, n = n0 + tx;
    tile[i][tx] = (k < K && n < N) ? in[(size_t)k * N + n] : 0.f;
  }
  __syncthreads();
  for (int i = ty; i < 32; i += 8) {
    int n = n0 + i, k = k0 + tx;
    if (n < Npad && k < K) out[(size_t)n * K + k] = f2bf(tile[tx][i]);
  }
}

// ---------------- common staging helper: 8 rows x 64k, swizzle key = row&7 ----------------
__device__ __forceinline__ void stage8(const u16* grow0, int ld, int kcol0,
                                       u16* lds_u, int ln) {
  int rr = ln >> 3, kb = ln & 7;
  gload_lds16(grow0 + (size_t)rr * ld + kcol0 + ((kb ^ rr) << 3), lds_u);
}

// =====================================================================================
// gemm8p: 256x256, BK=64, 128KB LDS, 8-phase, 1 block/CU (round-4/6 verified).
// __launch_bounds__(512,2): do NOT raise min-waves (4/EU caps 128 VGPR -> acc spills).
// =====================================================================================
#define LDA_FRAGS(mh, buf)                                                         \
  _Pragma("unroll") for (int mf = 0; mf < 4; ++mf)                                 \
  _Pragma("unroll") for (int kk = 0; kk < 2; ++kk)                                 \
    av[mf][kk] = *(const bf16x8*)(LA + (buf) * 16384 +                             \
        (wm * 128 + (mh) * 64 + mf * 16 + lr) * 64 + (((kk * 4 + lq) ^ key) << 3));

#define LDB_FRAGS(nh, buf)                                                         \
  _Pragma("unroll") for (int nf = 0; nf < 2; ++nf)                                 \
  _Pragma("unroll") for (int kk = 0; kk < 2; ++kk)                                 \
    bb[nh][nf][kk] = *(const bf16x8*)(LB + (buf) * 16384 +                         \
        (wn * 64 + (nh) * 32 + nf * 16 + lr) * 64 + (((kk * 4 + lq) ^ key) << 3));

#define MFMA_Q(mh, nh)                                                             \
  __builtin_amdgcn_s_setprio(1);                                                   \
  _Pragma("unroll") for (int mf = 0; mf < 4; ++mf)                                 \
  _Pragma("unroll") for (int nf = 0; nf < 2; ++nf)                                 \
  _Pragma("unroll") for (int kk = 0; kk < 2; ++kk)                                 \
    acc[(mh) * 4 + mf][(nh) * 2 + nf] = __builtin_amdgcn_mfma_f32_16x16x32_bf16(   \
        av[mf][kk], bb[nh][nf][kk], acc[(mh) * 4 + mf][(nh) * 2 + nf], 0, 0, 0);   \
  __builtin_amdgcn_s_setprio(0);

#define STAGE_A(unit, kt, buf)                                                     \
  _Pragma("unroll") for (int c = 0; c < 2; ++c) {                                  \
    int g = w * 2 + c;                                                             \
    int r0 = ((g < 8) ? g * 8 : (g - 8) * 8 + 128) + (unit) * 64;                  \
    stage8(Ag + (size_t)r0 * ldK, ldK, (kt) * 64, LA + (buf) * 16384 + r0 * 64, ln); \
  }

#define STAGE_B(half, kt, buf)                                                     \
  _Pragma("unroll") for (int c = 0; c < 2; ++c) {                                  \
    int g = w * 2 + c;                                                             \
    int r0 = (g >> 2) * 64 + (half) * 32 + (g & 3) * 8;                            \
    stage8(Bg + (size_t)r0 * ldK, ldK, (kt) * 64, LB + (buf) * 16384 + r0 * 64, ln); \
  }

template <int OUT_BF16, int EPI>  // EPI: 1 = +aux residual (f32), 2 = silu col>=cthresh
__global__ __launch_bounds__(512, 2) void gemm8p(const u16* __restrict__ A,
                                                 const u16* __restrict__ Bt,
                                                 void* __restrict__ Cout,
                                                 const float* __restrict__ aux,
                                                 int M, int N, int K, int cthresh) {
  __shared__ alignas(16) u16 lds[65536];
  u16* LA = lds;
  u16* LB = lds + 32768;
  int t = threadIdx.x;
  int w = t >> 6, ln = t & 63;
  int wm = w >> 2, wn = w & 3;
  int bn, bm;
  swz_block(gridDim.x, bn, bm);
  int lr = ln & 15, lq = ln >> 4, key = ln & 7;
  int ldK = K;
  int NT = K >> 6;
  const u16* Ag = A + (size_t)bm * 256 * ldK;
  const u16* Bg = Bt + (size_t)bn * 256 * ldK;
  f32x4 acc[8][4] = {};
  bf16x8 av[4][2], bb[2][2][2];

  STAGE_A(0, 0, 0); STAGE_B(0, 0, 0); STAGE_B(1, 0, 0); STAGE_A(1, 0, 0);
  int k1 = NT > 1 ? 1 : 0;
  STAGE_A(0, k1, 1); STAGE_B(0, k1, 1); STAGE_B(1, k1, 1);
  asm volatile("s_waitcnt vmcnt(6)" ::: "memory");
  __builtin_amdgcn_s_barrier();

  for (int T = 0; T < NT; ++T) {
    int b0 = T & 1, b1 = b0 ^ 1;
    int kt1 = (T + 1 < NT) ? T + 1 : NT - 1;
    int kt2 = (T + 2 < NT) ? T + 2 : NT - 1;
    LDA_FRAGS(0, b0);
    LDB_FRAGS(0, b0);
    STAGE_A(1, kt1, b1);
    __builtin_amdgcn_s_barrier();
    asm volatile("s_waitcnt lgkmcnt(0)" ::: "memory");
    MFMA_Q(0, 0);
    __builtin_amdgcn_s_barrier();
    LDB_FRAGS(1, b0);
    STAGE_A(0, kt2, b0);
    __builtin_amdgcn_s_barrier();
    asm volatile("s_waitcnt lgkmcnt(0)" ::: "memory");
    MFMA_Q(0, 1);
    __builtin_amdgcn_s_barrier();
    LDA_FRAGS(1, b0);
    STAGE_B(0, kt2, b0);
    __builtin_amdgcn_s_barrier();
    asm volatile("s_waitcnt lgkmcnt(0)" ::: "memory");
    MFMA_Q(1, 1);
    __builtin_amdgcn_s_barrier();
    STAGE_B(1, kt2, b0);
    asm volatile("s_waitcnt vmcnt(6)" ::: "memory");
    __builtin_amdgcn_s_barrier();
    MFMA_Q(1, 0);
    __builtin_amdgcn_s_barrier();
  }

  int crow0 = bm * 256 + wm * 128;
  int ccol0 = bn * 256 + wn * 64;
#pragma unroll
  for (int mf = 0; mf < 8; ++mf)
#pragma unroll
    for (int nf = 0; nf < 4; ++nf)
#pragma unroll
      for (int r = 0; r < 4; ++r) {
        int row = crow0 + mf * 16 + lq * 4 + r;
        int col = ccol0 + nf * 16 + lr;
        float v = acc[mf][nf][r];
        if (EPI == 1) v += aux[(size_t)row * N + col];
        if (EPI == 2 && col >= cthresh) v = v * sigmoidf_(v);
        if (OUT_BF16)
          ((u16*)Cout)[(size_t)row * N + col] = f2bf(v);
        else
          ((float*)Cout)[(size_t)row * N + col] = v;
      }
}

// =====================================================================================
// gemm128_res: BM=128 x BN=256, BK=64, 96KB LDS, 8-phase, residual fused, f32 out.
// (round-7 verified) counted wait vmcnt(5); WAR discipline identical to gemm8p.
// =====================================================================================
#define LDA128(mh, buf)                                                            \
  _Pragma("unroll") for (int mf2 = 0; mf2 < 2; ++mf2)                              \
  _Pragma("unroll") for (int kk = 0; kk < 2; ++kk)                                 \
    av[mf2][kk] = *(const bf16x8*)(LA + (buf) * 8192 +                             \
        (wm * 64 + (mh) * 32 + mf2 * 16 + lr) * 64 + (((kk * 4 + lq) ^ key) << 3));

#define LDB128(nh, buf, B_)                                                        \
  _Pragma("unroll") for (int nf2 = 0; nf2 < 2; ++nf2)                              \
  _Pragma("unroll") for (int kk = 0; kk < 2; ++kk)                                 \
    B_[nf2][kk] = *(const bf16x8*)(LB + (buf) * 16384 +                            \
        (wn * 64 + (nh) * 32 + nf2 * 16 + lr) * 64 + (((kk * 4 + lq) ^ key) << 3));

#define MFMA_Q128(mh, nh, B_)                                                      \
  __builtin_amdgcn_s_setprio(1);                                                   \
  _Pragma("unroll") for (int mf2 = 0; mf2 < 2; ++mf2)                              \
  _Pragma("unroll") for (int nf2 = 0; nf2 < 2; ++nf2)                              \
  _Pragma("unroll") for (int kk = 0; kk < 2; ++kk)                                 \
    acc[(mh) * 2 + mf2][(nh) * 2 + nf2] = __builtin_amdgcn_mfma_f32_16x16x32_bf16( \
        av[mf2][kk], B_[nf2][kk], acc[(mh) * 2 + mf2][(nh) * 2 + nf2], 0, 0, 0);   \
  __builtin_amdgcn_s_setprio(0);

#define STAGE_A128(unit, kt, buf)                                                  \
  {                                                                                \
    int r0 = (w >> 2) * 64 + (unit) * 32 + (w & 3) * 8;                            \
    stage8(Ag + (size_t)r0 * ldK, ldK, (kt) * 64, LA + (buf) * 8192 + r0 * 64, ln); \
  }

#define STAGE_B128(half, kt, buf)                                                  \
  _Pragma("unroll") for (int c = 0; c < 2; ++c) {                                  \
    int g = w * 2 + c;                                                             \
    int r0 = (g >> 2) * 64 + (half) * 32 + (g & 3) * 8;                            \
    stage8(Bg + (size_t)r0 * ldK, ldK, (kt) * 64, LB + (buf) * 16384 + r0 * 64, ln); \
  }

__global__ __launch_bounds__(512, 2) void gemm128_res(const u16* __restrict__ A,
                                                      const u16* __restrict__ Bt,
                                                      float* __restrict__ Cout,
                                                      const float* __restrict__ res,
                                                      int M, int N, int K) {
  __shared__ alignas(16) u16 lds[49152];
  u16* LA = lds;
  u16* LB = lds + 16384;
  int t = threadIdx.x;
  int w = t >> 6, ln = t & 63;
  int wm = w >> 2, wn = w & 3;
  int bn, bm;
  swz_block(gridDim.x, bn, bm);
  int lr = ln & 15, lq = ln >> 4, key = ln & 7;
  int ldK = K;
  int NT = K >> 6;
  const u16* Ag = A + (size_t)bm * 128 * ldK;
  const u16* Bg = Bt + (size_t)bn * 256 * ldK;
  f32x4 acc[4][4] = {};
  bf16x8 av[2][2], bbl[2][2], bbh[2][2];

  STAGE_A128(0, 0, 0); STAGE_B128(0, 0, 0); STAGE_B128(1, 0, 0); STAGE_A128(1, 0, 0);
  int k1 = NT > 1 ? 1 : 0;
  STAGE_A128(0, k1, 1); STAGE_B128(0, k1, 1); STAGE_B128(1, k1, 1);
  asm volatile("s_waitcnt vmcnt(5)" ::: "memory");
  __builtin_amdgcn_s_barrier();

  for (int T = 0; T < NT; ++T) {
    int b0 = T & 1, b1 = b0 ^ 1;
    int kt1 = (T + 1 < NT) ? T + 1 : NT - 1;
    int kt2 = (T + 2 < NT) ? T + 2 : NT - 1;
    LDA128(0, b0);
    LDB128(0, b0, bbl);
    STAGE_A128(1, kt1, b1);
    __builtin_amdgcn_s_barrier();
    asm volatile("s_waitcnt lgkmcnt(0)" ::: "memory");
    MFMA_Q128(0, 0, bbl);
    __builtin_amdgcn_s_barrier();
    LDB128(1, b0, bbh);
    STAGE_A128(0, kt2, b0);
    __builtin_amdgcn_s_barrier();
    asm volatile("s_waitcnt lgkmcnt(0)" ::: "memory");
    MFMA_Q128(0, 1, bbh);
    __builtin_amdgcn_s_barrier();
    LDA128(1, b0);
    STAGE_B128(0, kt2, b0);
    __builtin_amdgcn_s_barrier();
    asm volatile("s_waitcnt lgkmcnt(0)" ::: "memory");
    MFMA_Q128(1, 1, bbh);
    __builtin_amdgcn_s_barrier();
    STAGE_B128(1, kt2, b0);
    asm volatile("s_waitcnt vmcnt(5)" ::: "memory");
    __builtin_amdgcn_s_barrier();
    MFMA_Q128(1, 0, bbl);
    __builtin_amdgcn_s_barrier();
  }

  int crow0 = bm * 128 + wm * 64;
  int ccol0 = bn * 256 + wn * 64;
#pragma unroll
  for (int mf = 0; mf < 4; ++mf)
#pragma unroll
    for (int nf = 0; nf < 4; ++nf)
#pragma unroll
      for (int r = 0; r < 4; ++r) {
        int row = crow0 + mf * 16 + lq * 4 + r;
        int col = ccol0 + nf * 16 + lr;
        Cout[(size_t)row * N + col] = acc[mf][nf][r] + res[(size_t)row * N + col];
      }
}

// ---------------- 128x128 bf16 GEMM (small shapes) ----------------
// EPI: 0 none, 3 softplus(v + aux[col]); SPLITK: partials at z*M*N
template <int OUT_BF16, int EPI, int SPLITK>
__global__ __launch_bounds__(256) void gemm_bt(const u16* __restrict__ A,
                                               const u16* __restrict__ Bt,
                                               void* __restrict__ Cout,
                                               const float* __restrict__ aux,
                                               int M, int N, int K, int ld, int cthresh) {
  __shared__ alignas(16) u16 As[128 * 32];
  __shared__ alignas(16) u16 Bs[128 * 32];
  int t = threadIdx.x;
  int w = t >> 6, ln = t & 63;
  int wr = w >> 1, wc = w & 1;
  int bm = blockIdx.y, bn = blockIdx.x;
  int lr = ln & 15, lk = (ln >> 4) * 8;
  f32x4 acc[4][4] = {};
  int kz = SPLITK ? blockIdx.z * K : 0;
  const u16* Abase = A + (size_t)bm * 128 * ld + kz;
  const u16* Bbase = Bt + (size_t)bn * 128 * ld + kz;
  for (int k0 = 0; k0 < K; k0 += 32) {
#pragma unroll
    for (int c = 0; c < 2; ++c) {
      int chunk = w * 2 + c;
      int ee = chunk * 512 + ln * 8;
      int row = ee >> 5, col = ee & 31;
      gload_lds16(Abase + (size_t)row * ld + k0 + col, As + chunk * 512);
      gload_lds16(Bbase + (size_t)row * ld + k0 + col, Bs + chunk * 512);
    }
    __syncthreads();
    bf16x8 af[4], bfr[4];
#pragma unroll
    for (int m = 0; m < 4; ++m)
      af[m] = *(const bf16x8*)(As + (wr * 64 + m * 16 + lr) * 32 + lk);
#pragma unroll
    for (int n = 0; n < 4; ++n)
      bfr[n] = *(const bf16x8*)(Bs + (wc * 64 + n * 16 + lr) * 32 + lk);
#pragma unroll
    for (int m = 0; m < 4; ++m)
#pragma unroll
      for (int n = 0; n < 4; ++n)
        acc[m][n] = __builtin_amdgcn_mfma_f32_16x16x32_bf16(af[m], bfr[n], acc[m][n], 0, 0, 0);
    __syncthreads();
  }
  int rb = bm * 128 + wr * 64 + (ln >> 4) * 4;
  int cb = bn * 128 + wc * 64 + lr;
  float* Cpart = SPLITK ? ((float*)Cout + (size_t)blockIdx.z * M * N) : (float*)Cout;
#pragma unroll
  for (int m = 0; m < 4; ++m)
#pragma unroll
    for (int n = 0; n < 4; ++n)
#pragma unroll
      for (int r = 0; r < 4; ++r) {
        int row = rb + m * 16 + r;
        int col = cb + n * 16;
        float v = acc[m][n][r];
        if (EPI == 3) {
          float dtr = v + aux[col];
          v = dtr > 15.f ? dtr : __logf(1.f + __expf(dtr));
        }
        if (OUT_BF16)
          ((u16*)Cpart)[(size_t)row * N + col] = f2bf(v);
        else
          Cpart[(size_t)row * N + col] = v;
      }
}

// ---------------- reduce split-K partials -> xdbl f32, side-write dt_low bf16 ----------------
__global__ __launch_bounds__(256) void reduce_xdbl(const float* __restrict__ part,
                                                   float* __restrict__ xdbl,
                                                   u16* __restrict__ dtlow) {
  int i = blockIdx.x * 256 + threadIdx.x;
  float s = 0.f;
#pragma unroll
  for (int z = 0; z < 8; ++z) s += part[(size_t)z * (8192 * 128) + i];
  xdbl[i] = s;
  int col = i & 127;
  if (col < 64) dtlow[(size_t)(i >> 7) * 64 + col] = f2bf(s);
}

// ---------------- depthwise causal conv(4) + SiLU, 2 channels/thread ----------------
__global__ __launch_bounds__(256) void conv_silu(const u16* __restrict__ xz,
                                                 const float* __restrict__ cw,
                                                 const float* __restrict__ cb,
                                                 u16* __restrict__ out) {
  int d2 = blockIdx.x * 256 + threadIdx.x;  // channel pair
  int d = d2 * 2;
  int l0 = blockIdx.y * 8;
  int b = blockIdx.z;
  float w0a = cw[d * 4 + 0], w1a = cw[d * 4 + 1], w2a = cw[d * 4 + 2], w3a = cw[d * 4 + 3];
  float w0b = cw[d * 4 + 4], w1b = cw[d * 4 + 5], w2b = cw[d * 4 + 6], w3b = cw[d * 4 + 7];
  float biasa = cb[d], biasb = cb[d + 1];
  const u16* xp = xz + ((size_t)b * LSEQ) * 4096 + d;
  float xa[11], xb[11];
#pragma unroll
  for (int i = 0; i < 11; ++i) {
    int l = l0 - 3 + i;
    unsigned pk = (l >= 0) ? *(const unsigned*)(xp + (size_t)l * 4096) : 0u;
    xa[i] = bf2f((u16)(pk & 0xffffu));
    xb[i] = bf2f((u16)(pk >> 16));
  }
  u16* op = out + ((size_t)b * LSEQ + l0) * DINNER + d;
#pragma unroll
  for (int i = 0; i < 8; ++i) {
    float va = biasa + w0a * xa[i] + w1a * xa[i + 1] + w2a * xa[i + 2] + w3a * xa[i + 3];
    float vb = biasb + w0b * xb[i] + w1b * xb[i + 1] + w2b * xb[i + 2] + w3b * xb[i + 3];
    unsigned pk = (unsigned)f2bf(va * sigmoidf_(va)) |
                  ((unsigned)f2bf(vb * sigmoidf_(vb)) << 16);
    *(unsigned*)(op + (size_t)i * DINNER) = pk;
  }
}

// ---- compute a[16] = exp(dt*An[n]); fast path when An = -(n+1) (uniform branch) ----
__device__ __forceinline__ void compute_a(float dt, const float* An, bool fast, float* av) {
  if (fast) {
    float q = __expf(-dt);
    float q2 = q * q, q4 = q2 * q2;
    av[0] = q; av[1] = q2; av[2] = q2 * q; av[3] = q4;
#pragma unroll
    for (int n = 4; n < 16; ++n) av[n] = av[n - 4] * q4;
  } else {
#pragma unroll
    for (int n = 0; n < 16; ++n) av[n] = __expf(dt * An[n]);
  }
}

__device__ __forceinline__ void load_An(const float* A_log, int d, float* An, bool& fast) {
  const float4* A4 = (const float4*)(A_log + (size_t)d * 16);
  fast = true;
#pragma unroll
  for (int q = 0; q < 4; ++q) {
    float4 a = A4[q];
    An[q * 4 + 0] = -__expf(a.x);
    An[q * 4 + 1] = -__expf(a.y);
    An[q * 4 + 2] = -__expf(a.z);
    An[q * 4 + 3] = -__expf(a.w);
  }
#pragma unroll
  for (int n = 0; n < 16; ++n)
    fast = fast && (__builtin_fabsf(An[n] + (float)(n + 1)) < 1e-3f * (n + 1));
}

// ---------------- scan pass 1: local chunk scan, software-pipelined loads ----------------
__global__ __launch_bounds__(256) void scan1(const u16* __restrict__ dtbf,
                                             const u16* __restrict__ ubf,
                                             const float* __restrict__ xdbl,
                                             const float* __restrict__ A_log,
                                             float* __restrict__ P,
                                             float* __restrict__ H) {
  int d = blockIdx.x * 256 + threadIdx.x;
  int b = blockIdx.y, c = blockIdx.z;
  size_t row0 = (size_t)b * LSEQ + c * 64;
  float An[16];
  bool fast;
  load_An(A_log, d, An, fast);
  const u16* dtp = dtbf + row0 * DINNER + d;
  const u16* up = ubf + row0 * DINNER + d;
  const float* Bp = xdbl + row0 * 128 + 64;
  float h[16];
#pragma unroll
  for (int n = 0; n < 16; ++n) h[n] = 0.f;
  float sdt = 0.f;
  // prefetch step 0
  float dt_c = bf2f(dtp[0]);
  float uu_c = bf2f(up[0]);
  const float4* B4 = (const float4*)Bp;
  float4 b0c = B4[0], b1c = B4[1], b2c = B4[2], b3c = B4[3];
  for (int i = 0; i < 64; ++i) {
    float dt_n = dt_c, uu_n = uu_c;
    float4 b0n = b0c, b1n = b1c, b2n = b2c, b3n = b3c;
    if (i < 63) {
      dt_n = bf2f(dtp[(size_t)(i + 1) * DINNER]);
      uu_n = bf2f(up[(size_t)(i + 1) * DINNER]);
      const float4* B4n = (const float4*)(Bp + (size_t)(i + 1) * 128);
      b0n = B4n[0]; b1n = B4n[1]; b2n = B4n[2]; b3n = B4n[3];
    }
    float dtu = dt_c * uu_c;
    sdt += dt_c;
    float Bf[16] = {b0c.x, b0c.y, b0c.z, b0c.w, b1c.x, b1c.y, b1c.z, b1c.w,
                    b2c.x, b2c.y, b2c.z, b2c.w, b3c.x, b3c.y, b3c.z, b3c.w};
    float av[16];
    compute_a(dt_c, An, fast, av);
#pragma unroll
    for (int n = 0; n < 16; ++n) h[n] = av[n] * h[n] + dtu * Bf[n];
    dt_c = dt_n; uu_c = uu_n;
    b0c = b0n; b1c = b1n; b2c = b2n; b3c = b3n;
  }
  size_t idx = (size_t)c * 65536 + ((size_t)b * DINNER + d) * 16;
  float4* P4 = (float4*)(P + idx);
  float4* H4 = (float4*)(H + idx);
#pragma unroll
  for (int q = 0; q < 4; ++q) {
    P4[q] = make_float4(__expf(An[q * 4 + 0] * sdt), __expf(An[q * 4 + 1] * sdt),
                        __expf(An[q * 4 + 2] * sdt), __expf(An[q * 4 + 3] * sdt));
    H4[q] = make_float4(h[q * 4], h[q * 4 + 1], h[q * 4 + 2], h[q * 4 + 3]);
  }
}

// ---------------- scan pass 2 ----------------
__global__ __launch_bounds__(256) void scan2(const float* __restrict__ P,
                                             const float* __restrict__ H,
                                             float* __restrict__ Hinit) {
  int i = blockIdx.x * 256 + threadIdx.x;
  float h = 0.f;
  for (int c = 0; c < 64; ++c) {
    Hinit[(size_t)c * 65536 + i] = h;
    h = P[(size_t)c * 65536 + i] * h + H[(size_t)c * 65536 + i];
  }
}

// ---------------- scan pass 3: replay + D-term + gate, software-pipelined loads ----------
__global__ __launch_bounds__(256) void scan3(const u16* __restrict__ dtbf,
                                             const u16* __restrict__ ubf,
                                             const float* __restrict__ xdbl,
                                             const float* __restrict__ A_log,
                                             const float* __restrict__ Dp,
                                             const u16* __restrict__ xzbf,
                                             const float* __restrict__ Hinit,
                                             u16* __restrict__ ybf) {
  int d = blockIdx.x * 256 + threadIdx.x;
  int b = blockIdx.y, c = blockIdx.z;
  size_t row0 = (size_t)b * LSEQ + c * 64;
  float An[16];
  bool fast;
  load_An(A_log, d, An, fast);
  const u16* dtp = dtbf + row0 * DINNER + d;
  const u16* up = ubf + row0 * DINNER + d;
  const float* Bp = xdbl + row0 * 128 + 64;
  const float* Cp = xdbl + row0 * 128 + 80;
  const u16* gp = xzbf + row0 * 4096 + DINNER + d;
  u16* yp = ybf + row0 * DINNER + d;
  float Dv = Dp[d];
  float h[16];
  {
    const float4* Hi4 = (const float4*)(Hinit + (size_t)c * 65536 + ((size_t)b * DINNER + d) * 16);
#pragma unroll
    for (int q = 0; q < 4; ++q) {
      float4 hv = Hi4[q];
      h[q * 4 + 0] = hv.x; h[q * 4 + 1] = hv.y; h[q * 4 + 2] = hv.z; h[q * 4 + 3] = hv.w;
    }
  }
  // prefetch step 0
  float dt_c = bf2f(dtp[0]);
  float uu_c = bf2f(up[0]);
  float g_c = bf2f(gp[0]);
  const float4* B4 = (const float4*)Bp;
  const float4* C4 = (const float4*)Cp;
  float4 b0c = B4[0], b1c = B4[1], b2c = B4[2], b3c = B4[3];
  float4 c0c = C4[0], c1c = C4[1], c2c = C4[2], c3c = C4[3];
  for (int i = 0; i < 64; ++i) {
    float dt_n = dt_c, uu_n = uu_c, g_n = g_c;
    float4 b0n = b0c, b1n = b1c, b2n = b2c, b3n = b3c;
    float4 c0n = c0c, c1n = c1c, c2n = c2c, c3n = c3c;
    if (i < 63) {
      dt_n = bf2f(dtp[(size_t)(i + 1) * DINNER]);
      uu_n = bf2f(up[(size_t)(i + 1) * DINNER]);
      g_n = bf2f(gp[(size_t)(i + 1) * 4096]);
      const float4* B4n = (const float4*)(Bp + (size_t)(i + 1) * 128);
      const float4* C4n = (const float4*)(Cp + (size_t)(i + 1) * 128);
      b0n = B4n[0]; b1n = B4n[1]; b2n = B4n[2]; b3n = B4n[3];
      c0n = C4n[0]; c1n = C4n[1]; c2n = C4n[2]; c3n = C4n[3];
    }
    float dtu = dt_c * uu_c;
    float Bf[16] = {b0c.x, b0c.y, b0c.z, b0c.w, b1c.x, b1c.y, b1c.z, b1c.w,
                    b2c.x, b2c.y, b2c.z, b2c.w, b3c.x, b3c.y, b3c.z, b3c.w};
    float Cf[16] = {c0c.x, c0c.y, c0c.z, c0c.w, c1c.x, c1c.y, c1c.z, c1c.w,
                    c2c.x, c2c.y, c2c.z, c2c.w, c3c.x, c3c.y, c3c.z, c3c.w};
    float av[16];
    compute_a(dt_c, An, fast, av);
    float y = 0.f;
#pragma unroll
    for (int n = 0; n < 16; ++n) {
      h[n] = av[n] * h[n] + dtu * Bf[n];
      y += h[n] * Cf[n];
    }
    yp[(size_t)i * DINNER] = f2bf((y + uu_c * Dv) * g_c);
    dt_c = dt_n; uu_c = uu_n; g_c = g_n;
    b0c = b0n; b1c = b1n; b2c = b2n; b3c = b3n;
    c0c = c0n; c1c = c1n; c2c = c2n; c3c = c3n;
  }
}

extern "C" void kernel_launch(void* const* d_in, const int* in_sizes, int n_in,
                              void* d_out, int out_size, void* d_ws, size_t ws_size,
                              hipStream_t stream) {
  const float* x = (const float*)d_in[0];
  const float* nw = (const float*)d_in[1];
  const float* nb = (const float*)d_in[2];
  const float* W_in = (const float*)d_in[3];
  const float* convw = (const float*)d_in[4];
  const float* convb = (const float*)d_in[5];
  const float* W_x = (const float*)d_in[6];
  const float* W_dt = (const float*)d_in[7];
  const float* b_dt = (const float*)d_in[8];
  const float* A_log = (const float*)d_in[9];
  const float* Dp = (const float*)d_in[10];
  const float* W_out = (const float*)d_in[11];
  float* out = (float*)d_out;

  char* wp = (char*)d_ws;
  auto alloc = [&](size_t bytes) {
    char* p = wp;
    wp += (bytes + 255) & ~(size_t)255;
    return p;
  };
  u16* xz_bf = (u16*)alloc((size_t)8192 * 4096 * 2);     // x half raw, z half silu'd
  u16* xconv_bf = (u16*)alloc((size_t)8192 * 2048 * 2);  // u
  u16* xn_bf = (u16*)alloc((size_t)8192 * 1024 * 2);
  float* xdbl = (float*)alloc((size_t)8192 * 128 * 4);
  u16* dt_bf = (u16*)alloc((size_t)8192 * 2048 * 2);     // softplus'd dt
  u16* dtlow_bf = (u16*)alloc((size_t)8192 * 64 * 2);
  u16* Wint = (u16*)alloc((size_t)4096 * 1024 * 2);
  u16* Wxt = (u16*)alloc((size_t)128 * 2048 * 2);
  u16* Wdtt = (u16*)alloc((size_t)2048 * 64 * 2);
  u16* Woutt = (u16*)alloc((size_t)1024 * 2048 * 2);
  float* P = (float*)alloc((size_t)64 * 65536 * 4);
  float* H = (float*)alloc((size_t)64 * 65536 * 4);
  float* Hinit = (float*)alloc((size_t)64 * 65536 * 4);
  // overlays:
  float* xdbl_part = (float*)P;  // split-K partials for W_x gemm, dead before scan1
  u16* y_bf = (u16*)P;           // scan3 output over P+H (P,H dead after scan2)

  // weight prep (B^T bf16), single fused launch
  tc_all<<<6528, 256, 0, stream>>>(W_in, W_x, W_dt, W_out, Wint, Wxt, Wdtt, Woutt);

  ln_kernel<<<8192, 256, 0, stream>>>(x, nw, nb, xn_bf);
  // xz = xn @ W_in, z-half silu'd in epilogue  (256^2 8-phase)
  gemm8p<1, 2><<<dim3(16, 32), 512, 0, stream>>>(xn_bf, Wint, xz_bf, nullptr,
                                                 8192, 4096, 1024, 2048);
  conv_silu<<<dim3(4, 512, 2), 256, 0, stream>>>(xz_bf, convw, convb, xconv_bf);
  // x_dbl = x_conv @ W_x : split-K x8 partials, then reduce (+ dt_low bf16 side-write)
  gemm_bt<0, 0, 1><<<dim3(1, 64, 8), 256, 0, stream>>>(xconv_bf, Wxt, xdbl_part, nullptr,
                                                       8192, 128, 256, 2048, 0);
  reduce_xdbl<<<4096, 256, 0, stream>>>(xdbl_part, xdbl, dtlow_bf);
  // dt = softplus(dt_low @ W_dt + b_dt)
  gemm_bt<1, 3, 0><<<dim3(16, 64), 256, 0, stream>>>(dtlow_bf, Wdtt, dt_bf, b_dt,
                                                     8192, 2048, 64, 64, 0);
  scan1<<<dim3(8, 2, 64), 256, 0, stream>>>(dt_bf, xconv_bf, xdbl, A_log, P, H);
  scan2<<<256, 256, 0, stream>>>(P, H, Hinit);
  scan3<<<dim3(8, 2, 64), 256, 0, stream>>>(dt_bf, xconv_bf, xdbl, A_log, Dp, xz_bf,
                                            Hinit, y_bf);
  // out = residual + y @ W_out  (128x256 tile, full machine in one round)
  gemm128_res<<<dim3(4, 64), 512, 0, stream>>>(y_bf, Woutt, out, x, 8192, 1024, 2048);
}

// Round 9
// 310.992 us; speedup vs baseline: 2.9536x; 1.0075x over previous
//
#include <hip/hip_runtime.h>

typedef unsigned short u16;
typedef __attribute__((ext_vector_type(8))) __bf16 bf16x8;
typedef __attribute__((ext_vector_type(4))) float f32x4;

#define LSEQ 4096
#define DMODEL 1024
#define DINNER 2048

__device__ __forceinline__ float bf2f(u16 u) {
  union { unsigned u; float f; } v; v.u = ((unsigned)u) << 16; return v.f;
}
__device__ __forceinline__ u16 f2bf(float f) {
  union { float f; unsigned u; } v; v.f = f;
  unsigned r = v.u + 0x7fffu + ((v.u >> 16) & 1u);
  return (u16)(r >> 16);
}
__device__ __forceinline__ void gload_lds16(const void* g, void* l) {
  __builtin_amdgcn_global_load_lds(
      (__attribute__((address_space(1))) void*)(unsigned long long)g,
      (__attribute__((address_space(3))) void*)(unsigned int)(unsigned long long)l,
      16, 0, 0);
}
__device__ __forceinline__ float sigmoidf_(float v) { return 1.f / (1.f + __expf(-v)); }

// bijective XCD swizzle (nwg % 8 == 0)
__device__ __forceinline__ void swz_block(int gx, int& bn, int& bm) {
  int lin = blockIdx.x + gridDim.x * blockIdx.y;
  int q = (gridDim.x * gridDim.y) >> 3;
  int s = (lin & 7) * q + (lin >> 3);
  bn = s % gx;
  bm = s / gx;
}

// ---------------- LayerNorm -> bf16 ----------------
__global__ __launch_bounds__(256) void ln_kernel(const float* __restrict__ x,
                                                 const float* __restrict__ w,
                                                 const float* __restrict__ b,
                                                 u16* __restrict__ out) {
  int row = blockIdx.x;
  const float* xr = x + (size_t)row * DMODEL;
  int t = threadIdx.x;
  float4 v = ((const float4*)xr)[t];
  float s = v.x + v.y + v.z + v.w;
  float s2 = v.x * v.x + v.y * v.y + v.z * v.z + v.w * v.w;
  for (int off = 32; off; off >>= 1) {
    s += __shfl_down(s, off);
    s2 += __shfl_down(s2, off);
  }
  __shared__ float ls[4], ls2[4];
  int wid = t >> 6;
  if ((t & 63) == 0) { ls[wid] = s; ls2[wid] = s2; }
  __syncthreads();
  s = ls[0] + ls[1] + ls[2] + ls[3];
  s2 = ls2[0] + ls2[1] + ls2[2] + ls2[3];
  float mu = s * (1.f / DMODEL);
  float var = s2 * (1.f / DMODEL) - mu * mu;
  float rs = rsqrtf(var + 1e-5f);
  float4 wv = ((const float4*)w)[t];
  float4 bv = ((const float4*)b)[t];
  unsigned p0 = (unsigned)f2bf((v.x - mu) * rs * wv.x + bv.x) |
                ((unsigned)f2bf((v.y - mu) * rs * wv.y + bv.y) << 16);
  unsigned p1 = (unsigned)f2bf((v.z - mu) * rs * wv.z + bv.z) |
                ((unsigned)f2bf((v.w - mu) * rs * wv.w + bv.w) << 16);
  ((uint2*)(out + (size_t)row * DMODEL))[t] = make_uint2(p0, p1);
}

// ---------------- fused transpose+cast for all 4 weights (one launch) ----------------
__global__ __launch_bounds__(256) void tc_all(const float* __restrict__ W_in,
                                              const float* __restrict__ W_x,
                                              const float* __restrict__ W_dt,
                                              const float* __restrict__ W_out,
                                              u16* __restrict__ o0, u16* __restrict__ o1,
                                              u16* __restrict__ o2, u16* __restrict__ o3) {
  __shared__ float tile[32][33];
  int id = blockIdx.x;
  const float* in;
  u16* out;
  int K, N, Npad, gx, bx;
  if (id < 4096)      { in = W_in;  out = o0; K = 1024; N = 4096; Npad = 4096; gx = 128; bx = id; }
  else if (id < 4352) { in = W_x;   out = o1; K = 2048; N = 96;   Npad = 128;  gx = 4;   bx = id - 4096; }
  else if (id < 4480) { in = W_dt;  out = o2; K = 64;   N = 2048; Npad = 2048; gx = 64;  bx = id - 4352; }
  else                { in = W_out; out = o3; K = 2048; N = 1024; Npad = 1024; gx = 32;  bx = id - 4480; }
  int n0 = (bx % gx) * 32, k0 = (bx / gx) * 32;
  int tx = threadIdx.x & 31, ty = threadIdx.x >> 5;
  for (int i = ty; i < 32; i += 8) {
    int k = k0 + i, n = n0 + tx;
    tile[i][tx] = (k < K && n < N) ? in[(size_t)k * N + n] : 0.f;
  }
  __syncthreads();
  for (int i = ty; i < 32; i += 8) {
    int n = n0 + i, k = k0 + tx;
    if (n < Npad && k < K) out[(size_t)n * K + k] = f2bf(tile[tx][i]);
  }
}

// ---------------- common staging helper: 8 rows x 64k, swizzle key = row&7 ----------------
__device__ __forceinline__ void stage8(const u16* grow0, int ld, int kcol0,
                                       u16* lds_u, int ln) {
  int rr = ln >> 3, kb = ln & 7;
  gload_lds16(grow0 + (size_t)rr * ld + kcol0 + ((kb ^ rr) << 3), lds_u);
}

// =====================================================================================
// gemm8p: 256x256, BK=64, 128KB LDS, 8-phase, 1 block/CU.
// Round-9 changes: (a) ds_read addressing via 4 precomputed lane pointers + literal-BUF
// unroll-by-2 -> all frag reads are base + 16-bit imm offset; (b) ONE barrier per phase
// (post-MFMA). Safety: lgkmcnt(0) asm (memory clobber) pins all frag reads before each
// MFMA, so reads of phase p are complete before any wave passes p's closing barrier;
// stages in p+1 targeting p-read regions stay WAR-safe. RAW across tiles unchanged:
// vmcnt(6)+barrier at P3 confirms tile T+1 data before its first read.
// __launch_bounds__(512,2): do NOT raise min-waves (4/EU caps 128 VGPR -> acc spills).
// =====================================================================================
#define LDA_F(mh, BUF)                                                             \
  _Pragma("unroll") for (int mf = 0; mf < 4; ++mf) {                               \
    av[mf][0] = *(const bf16x8*)(qA0 + (BUF) * 16384 + ((mh) * 64 + mf * 16) * 64); \
    av[mf][1] = *(const bf16x8*)(qA1 + (BUF) * 16384 + ((mh) * 64 + mf * 16) * 64); \
  }

#define LDB_F(nh, BUF)                                                             \
  _Pragma("unroll") for (int nf = 0; nf < 2; ++nf) {                               \
    bb[nh][nf][0] = *(const bf16x8*)(qB0 + (BUF) * 16384 + ((nh) * 32 + nf * 16) * 64); \
    bb[nh][nf][1] = *(const bf16x8*)(qB1 + (BUF) * 16384 + ((nh) * 32 + nf * 16) * 64); \
  }

#define MFMA_Q(mh, nh)                                                             \
  __builtin_amdgcn_s_setprio(1);                                                   \
  _Pragma("unroll") for (int mf = 0; mf < 4; ++mf)                                 \
  _Pragma("unroll") for (int nf = 0; nf < 2; ++nf)                                 \
  _Pragma("unroll") for (int kk = 0; kk < 2; ++kk)                                 \
    acc[(mh) * 4 + mf][(nh) * 2 + nf] = __builtin_amdgcn_mfma_f32_16x16x32_bf16(   \
        av[mf][kk], bb[nh][nf][kk], acc[(mh) * 4 + mf][(nh) * 2 + nf], 0, 0, 0);   \
  __builtin_amdgcn_s_setprio(0);

#define STAGE_A(unit, kt, buf)                                                     \
  _Pragma("unroll") for (int c = 0; c < 2; ++c) {                                  \
    int g = w * 2 + c;                                                             \
    int r0 = ((g < 8) ? g * 8 : (g - 8) * 8 + 128) + (unit) * 64;                  \
    stage8(Ag + (size_t)r0 * ldK, ldK, (kt) * 64, LA + (buf) * 16384 + r0 * 64, ln); \
  }

#define STAGE_B(half, kt, buf)                                                     \
  _Pragma("unroll") for (int c = 0; c < 2; ++c) {                                  \
    int g = w * 2 + c;                                                             \
    int r0 = (g >> 2) * 64 + (half) * 32 + (g & 3) * 8;                            \
    stage8(Bg + (size_t)r0 * ldK, ldK, (kt) * 64, LB + (buf) * 16384 + r0 * 64, ln); \
  }

#define PHASES8P(T_, B0_, B1_)                                                     \
  {                                                                                \
    int kt1 = ((T_) + 1 < NT) ? (T_) + 1 : NT - 1;                                 \
    int kt2 = ((T_) + 2 < NT) ? (T_) + 2 : NT - 1;                                 \
    LDA_F(0, B0_); LDB_F(0, B0_);                                                  \
    STAGE_A(1, kt1, B1_);                                                          \
    asm volatile("s_waitcnt lgkmcnt(0)" ::: "memory");                             \
    MFMA_Q(0, 0);                                                                  \
    __builtin_amdgcn_s_barrier();                                                  \
    LDB_F(1, B0_);                                                                 \
    STAGE_A(0, kt2, B0_);                                                          \
    asm volatile("s_waitcnt lgkmcnt(0)" ::: "memory");                             \
    MFMA_Q(0, 1);                                                                  \
    __builtin_amdgcn_s_barrier();                                                  \
    LDA_F(1, B0_);                                                                 \
    STAGE_B(0, kt2, B0_);                                                          \
    asm volatile("s_waitcnt lgkmcnt(0)" ::: "memory");                             \
    MFMA_Q(1, 1);                                                                  \
    __builtin_amdgcn_s_barrier();                                                  \
    STAGE_B(1, kt2, B0_);                                                          \
    asm volatile("s_waitcnt vmcnt(6)" ::: "memory");                               \
    MFMA_Q(1, 0);                                                                  \
    __builtin_amdgcn_s_barrier();                                                  \
  }

template <int OUT_BF16, int EPI>  // EPI: 1 = +aux residual (f32), 2 = silu col>=cthresh
__global__ __launch_bounds__(512, 2) void gemm8p(const u16* __restrict__ A,
                                                 const u16* __restrict__ Bt,
                                                 void* __restrict__ Cout,
                                                 const float* __restrict__ aux,
                                                 int M, int N, int K, int cthresh) {
  __shared__ alignas(16) u16 lds[65536];
  u16* LA = lds;
  u16* LB = lds + 32768;
  int t = threadIdx.x;
  int w = t >> 6, ln = t & 63;
  int wm = w >> 2, wn = w & 3;
  int bn, bm;
  swz_block(gridDim.x, bn, bm);
  int lr = ln & 15, lq = ln >> 4, key = ln & 7;
  int ldK = K;
  int NT = K >> 6;
  const u16* Ag = A + (size_t)bm * 256 * ldK;
  const u16* Bg = Bt + (size_t)bn * 256 * ldK;
  const u16* qA0 = LA + (wm * 128 + lr) * 64 + ((lq ^ key) << 3);
  const u16* qA1 = LA + (wm * 128 + lr) * 64 + (((4 + lq) ^ key) << 3);
  const u16* qB0 = LB + (wn * 64 + lr) * 64 + ((lq ^ key) << 3);
  const u16* qB1 = LB + (wn * 64 + lr) * 64 + (((4 + lq) ^ key) << 3);
  f32x4 acc[8][4] = {};
  bf16x8 av[4][2], bb[2][2][2];

  STAGE_A(0, 0, 0); STAGE_B(0, 0, 0); STAGE_B(1, 0, 0); STAGE_A(1, 0, 0);
  int k1 = NT > 1 ? 1 : 0;
  STAGE_A(0, k1, 1); STAGE_B(0, k1, 1); STAGE_B(1, k1, 1);
  asm volatile("s_waitcnt vmcnt(6)" ::: "memory");
  __builtin_amdgcn_s_barrier();

  for (int TT = 0; TT < NT; TT += 2) {  // NT is even (K multiple of 128)
    PHASES8P(TT, 0, 1)
    PHASES8P(TT + 1, 1, 0)
  }

  int crow0 = bm * 256 + wm * 128;
  int ccol0 = bn * 256 + wn * 64;
#pragma unroll
  for (int mf = 0; mf < 8; ++mf)
#pragma unroll
    for (int nf = 0; nf < 4; ++nf)
#pragma unroll
      for (int r = 0; r < 4; ++r) {
        int row = crow0 + mf * 16 + lq * 4 + r;
        int col = ccol0 + nf * 16 + lr;
        float v = acc[mf][nf][r];
        if (EPI == 1) v += aux[(size_t)row * N + col];
        if (EPI == 2 && col >= cthresh) v = v * sigmoidf_(v);
        if (OUT_BF16)
          ((u16*)Cout)[(size_t)row * N + col] = f2bf(v);
        else
          ((float*)Cout)[(size_t)row * N + col] = v;
      }
}

// =====================================================================================
// gemm128_res: BM=128 x BN=256, BK=64, 96KB LDS, 8-phase, residual fused, f32 out.
// Same round-9 restructure; counted wait vmcnt(5).
// =====================================================================================
#define LDA128(mh, BUF)                                                            \
  _Pragma("unroll") for (int mf2 = 0; mf2 < 2; ++mf2) {                            \
    av[mf2][0] = *(const bf16x8*)(rA0 + (BUF) * 8192 + ((mh) * 32 + mf2 * 16) * 64); \
    av[mf2][1] = *(const bf16x8*)(rA1 + (BUF) * 8192 + ((mh) * 32 + mf2 * 16) * 64); \
  }

#define LDB128(nh, BUF, B_)                                                        \
  _Pragma("unroll") for (int nf2 = 0; nf2 < 2; ++nf2) {                            \
    B_[nf2][0] = *(const bf16x8*)(rB0 + (BUF) * 16384 + ((nh) * 32 + nf2 * 16) * 64); \
    B_[nf2][1] = *(const bf16x8*)(rB1 + (BUF) * 16384 + ((nh) * 32 + nf2 * 16) * 64); \
  }

#define MFMA_Q128(mh, nh, B_)                                                      \
  __builtin_amdgcn_s_setprio(1);                                                   \
  _Pragma("unroll") for (int mf2 = 0; mf2 < 2; ++mf2)                              \
  _Pragma("unroll") for (int nf2 = 0; nf2 < 2; ++nf2)                              \
  _Pragma("unroll") for (int kk = 0; kk < 2; ++kk)                                 \
    acc[(mh) * 2 + mf2][(nh) * 2 + nf2] = __builtin_amdgcn_mfma_f32_16x16x32_bf16( \
        av[mf2][kk], B_[nf2][kk], acc[(mh) * 2 + mf2][(nh) * 2 + nf2], 0, 0, 0);   \
  __builtin_amdgcn_s_setprio(0);

#define STAGE_A128(unit, kt, buf)                                                  \
  {                                                                                \
    int r0 = (w >> 2) * 64 + (unit) * 32 + (w & 3) * 8;                            \
    stage8(Ag + (size_t)r0 * ldK, ldK, (kt) * 64, LA + (buf) * 8192 + r0 * 64, ln); \
  }

#define STAGE_B128(half, kt, buf)                                                  \
  _Pragma("unroll") for (int c = 0; c < 2; ++c) {                                  \
    int g = w * 2 + c;                                                             \
    int r0 = (g >> 2) * 64 + (half) * 32 + (g & 3) * 8;                            \
    stage8(Bg + (size_t)r0 * ldK, ldK, (kt) * 64, LB + (buf) * 16384 + r0 * 64, ln); \
  }

#define PHASES128(T_, B0_, B1_)                                                    \
  {                                                                                \
    int kt1 = ((T_) + 1 < NT) ? (T_) + 1 : NT - 1;                                 \
    int kt2 = ((T_) + 2 < NT) ? (T_) + 2 : NT - 1;                                 \
    LDA128(0, B0_);                                                                \
    LDB128(0, B0_, bbl);                                                           \
    STAGE_A128(1, kt1, B1_);                                                       \
    asm volatile("s_waitcnt lgkmcnt(0)" ::: "memory");                             \
    MFMA_Q128(0, 0, bbl);                                                          \
    __builtin_amdgcn_s_barrier();                                                  \
    LDB128(1, B0_, bbh);                                                           \
    STAGE_A128(0, kt2, B0_);                                                       \
    asm volatile("s_waitcnt lgkmcnt(0)" ::: "memory");                             \
    MFMA_Q128(0, 1, bbh);                                                          \
    __builtin_amdgcn_s_barrier();                                                  \
    LDA128(1, B0_);                                                                \
    STAGE_B128(0, kt2, B0_);                                                       \
    asm volatile("s_waitcnt lgkmcnt(0)" ::: "memory");                             \
    MFMA_Q128(1, 1, bbh);                                                          \
    __builtin_amdgcn_s_barrier();                                                  \
    STAGE_B128(1, kt2, B0_);                                                       \
    asm volatile("s_waitcnt vmcnt(5)" ::: "memory");                               \
    MFMA_Q128(1, 0, bbl);                                                          \
    __builtin_amdgcn_s_barrier();                                                  \
  }

__global__ __launch_bounds__(512, 2) void gemm128_res(const u16* __restrict__ A,
                                                      const u16* __restrict__ Bt,
                                                      float* __restrict__ Cout,
                                                      const float* __restrict__ res,
                                                      int M, int N, int K) {
  __shared__ alignas(16) u16 lds[49152];
  u16* LA = lds;
  u16* LB = lds + 16384;
  int t = threadIdx.x;
  int w = t >> 6, ln = t & 63;
  int wm = w >> 2, wn = w & 3;
  int bn, bm;
  swz_block(gridDim.x, bn, bm);
  int lr = ln & 15, lq = ln >> 4, key = ln & 7;
  int ldK = K;
  int NT = K >> 6;
  const u16* Ag = A + (size_t)bm * 128 * ldK;
  const u16* Bg = Bt + (size_t)bn * 256 * ldK;
  const u16* rA0 = LA + (wm * 64 + lr) * 64 + ((lq ^ key) << 3);
  const u16* rA1 = LA + (wm * 64 + lr) * 64 + (((4 + lq) ^ key) << 3);
  const u16* rB0 = LB + (wn * 64 + lr) * 64 + ((lq ^ key) << 3);
  const u16* rB1 = LB + (wn * 64 + lr) * 64 + (((4 + lq) ^ key) << 3);
  f32x4 acc[4][4] = {};
  bf16x8 av[2][2], bbl[2][2], bbh[2][2];

  STAGE_A128(0, 0, 0); STAGE_B128(0, 0, 0); STAGE_B128(1, 0, 0); STAGE_A128(1, 0, 0);
  int k1 = NT > 1 ? 1 : 0;
  STAGE_A128(0, k1, 1); STAGE_B128(0, k1, 1); STAGE_B128(1, k1, 1);
  asm volatile("s_waitcnt vmcnt(5)" ::: "memory");
  __builtin_amdgcn_s_barrier();

  for (int TT = 0; TT < NT; TT += 2) {
    PHASES128(TT, 0, 1)
    PHASES128(TT + 1, 1, 0)
  }

  int crow0 = bm * 128 + wm * 64;
  int ccol0 = bn * 256 + wn * 64;
#pragma unroll
  for (int mf = 0; mf < 4; ++mf)
#pragma unroll
    for (int nf = 0; nf < 4; ++nf)
#pragma unroll
      for (int r = 0; r < 4; ++r) {
        int row = crow0 + mf * 16 + lq * 4 + r;
        int col = ccol0 + nf * 16 + lr;
        Cout[(size_t)row * N + col] = acc[mf][nf][r] + res[(size_t)row * N + col];
      }
}

// ---------------- 128x128 bf16 GEMM (small shapes) ----------------
template <int OUT_BF16, int EPI, int SPLITK>
__global__ __launch_bounds__(256) void gemm_bt(const u16* __restrict__ A,
                                               const u16* __restrict__ Bt,
                                               void* __restrict__ Cout,
                                               const float* __restrict__ aux,
                                               int M, int N, int K, int ld, int cthresh) {
  __shared__ alignas(16) u16 As[128 * 32];
  __shared__ alignas(16) u16 Bs[128 * 32];
  int t = threadIdx.x;
  int w = t >> 6, ln = t & 63;
  int wr = w >> 1, wc = w & 1;
  int bm = blockIdx.y, bn = blockIdx.x;
  int lr = ln & 15, lk = (ln >> 4) * 8;
  f32x4 acc[4][4] = {};
  int kz = SPLITK ? blockIdx.z * K : 0;
  const u16* Abase = A + (size_t)bm * 128 * ld + kz;
  const u16* Bbase = Bt + (size_t)bn * 128 * ld + kz;
  for (int k0 = 0; k0 < K; k0 += 32) {
#pragma unroll
    for (int c = 0; c < 2; ++c) {
      int chunk = w * 2 + c;
      int ee = chunk * 512 + ln * 8;
      int row = ee >> 5, col = ee & 31;
      gload_lds16(Abase + (size_t)row * ld + k0 + col, As + chunk * 512);
      gload_lds16(Bbase + (size_t)row * ld + k0 + col, Bs + chunk * 512);
    }
    __syncthreads();
    bf16x8 af[4], bfr[4];
#pragma unroll
    for (int m = 0; m < 4; ++m)
      af[m] = *(const bf16x8*)(As + (wr * 64 + m * 16 + lr) * 32 + lk);
#pragma unroll
    for (int n = 0; n < 4; ++n)
      bfr[n] = *(const bf16x8*)(Bs + (wc * 64 + n * 16 + lr) * 32 + lk);
#pragma unroll
    for (int m = 0; m < 4; ++m)
#pragma unroll
      for (int n = 0; n < 4; ++n)
        acc[m][n] = __builtin_amdgcn_mfma_f32_16x16x32_bf16(af[m], bfr[n], acc[m][n], 0, 0, 0);
    __syncthreads();
  }
  int rb = bm * 128 + wr * 64 + (ln >> 4) * 4;
  int cb = bn * 128 + wc * 64 + lr;
  float* Cpart = SPLITK ? ((float*)Cout + (size_t)blockIdx.z * M * N) : (float*)Cout;
#pragma unroll
  for (int m = 0; m < 4; ++m)
#pragma unroll
    for (int n = 0; n < 4; ++n)
#pragma unroll
      for (int r = 0; r < 4; ++r) {
        int row = rb + m * 16 + r;
        int col = cb + n * 16;
        float v = acc[m][n][r];
        if (EPI == 3) {
          float dtr = v + aux[col];
          v = dtr > 15.f ? dtr : __logf(1.f + __expf(dtr));
        }
        if (OUT_BF16)
          ((u16*)Cpart)[(size_t)row * N + col] = f2bf(v);
        else
          Cpart[(size_t)row * N + col] = v;
      }
}

// ---------------- reduce split-K partials -> xdbl f32, side-write dt_low bf16 ----------------
__global__ __launch_bounds__(256) void reduce_xdbl(const float* __restrict__ part,
                                                   float* __restrict__ xdbl,
                                                   u16* __restrict__ dtlow) {
  int i = blockIdx.x * 256 + threadIdx.x;
  float s = 0.f;
#pragma unroll
  for (int z = 0; z < 8; ++z) s += part[(size_t)z * (8192 * 128) + i];
  xdbl[i] = s;
  int col = i & 127;
  if (col < 64) dtlow[(size_t)(i >> 7) * 64 + col] = f2bf(s);
}

// ---------------- depthwise causal conv(4) + SiLU, 2 channels/thread ----------------
__global__ __launch_bounds__(256) void conv_silu(const u16* __restrict__ xz,
                                                 const float* __restrict__ cw,
                                                 const float* __restrict__ cb,
                                                 u16* __restrict__ out) {
  int d2 = blockIdx.x * 256 + threadIdx.x;
  int d = d2 * 2;
  int l0 = blockIdx.y * 8;
  int b = blockIdx.z;
  float w0a = cw[d * 4 + 0], w1a = cw[d * 4 + 1], w2a = cw[d * 4 + 2], w3a = cw[d * 4 + 3];
  float w0b = cw[d * 4 + 4], w1b = cw[d * 4 + 5], w2b = cw[d * 4 + 6], w3b = cw[d * 4 + 7];
  float biasa = cb[d], biasb = cb[d + 1];
  const u16* xp = xz + ((size_t)b * LSEQ) * 4096 + d;
  float xa[11], xb[11];
#pragma unroll
  for (int i = 0; i < 11; ++i) {
    int l = l0 - 3 + i;
    unsigned pk = (l >= 0) ? *(const unsigned*)(xp + (size_t)l * 4096) : 0u;
    xa[i] = bf2f((u16)(pk & 0xffffu));
    xb[i] = bf2f((u16)(pk >> 16));
  }
  u16* op = out + ((size_t)b * LSEQ + l0) * DINNER + d;
#pragma unroll
  for (int i = 0; i < 8; ++i) {
    float va = biasa + w0a * xa[i] + w1a * xa[i + 1] + w2a * xa[i + 2] + w3a * xa[i + 3];
    float vb = biasb + w0b * xb[i] + w1b * xb[i + 1] + w2b * xb[i + 2] + w3b * xb[i + 3];
    unsigned pk = (unsigned)f2bf(va * sigmoidf_(va)) |
                  ((unsigned)f2bf(vb * sigmoidf_(vb)) << 16);
    *(unsigned*)(op + (size_t)i * DINNER) = pk;
  }
}

// ---- compute a[16] = exp(dt*An[n]); fast path when An = -(n+1) (uniform branch) ----
__device__ __forceinline__ void compute_a(float dt, const float* An, bool fast, float* av) {
  if (fast) {
    float q = __expf(-dt);
    float q2 = q * q, q4 = q2 * q2;
    av[0] = q; av[1] = q2; av[2] = q2 * q; av[3] = q4;
#pragma unroll
    for (int n = 4; n < 16; ++n) av[n] = av[n - 4] * q4;
  } else {
#pragma unroll
    for (int n = 0; n < 16; ++n) av[n] = __expf(dt * An[n]);
  }
}

__device__ __forceinline__ void load_An(const float* A_log, int d, float* An, bool& fast) {
  const float4* A4 = (const float4*)(A_log + (size_t)d * 16);
  fast = true;
#pragma unroll
  for (int q = 0; q < 4; ++q) {
    float4 a = A4[q];
    An[q * 4 + 0] = -__expf(a.x);
    An[q * 4 + 1] = -__expf(a.y);
    An[q * 4 + 2] = -__expf(a.z);
    An[q * 4 + 3] = -__expf(a.w);
  }
#pragma unroll
  for (int n = 0; n < 16; ++n)
    fast = fast && (__builtin_fabsf(An[n] + (float)(n + 1)) < 1e-3f * (n + 1));
}

// ---------------- scan pass 1: local chunk scan, software-pipelined loads ----------------
__global__ __launch_bounds__(256) void scan1(const u16* __restrict__ dtbf,
                                             const u16* __restrict__ ubf,
                                             const float* __restrict__ xdbl,
                                             const float* __restrict__ A_log,
                                             float* __restrict__ P,
                                             float* __restrict__ H) {
  int d = blockIdx.x * 256 + threadIdx.x;
  int b = blockIdx.y, c = blockIdx.z;
  size_t row0 = (size_t)b * LSEQ + c * 64;
  float An[16];
  bool fast;
  load_An(A_log, d, An, fast);
  const u16* dtp = dtbf + row0 * DINNER + d;
  const u16* up = ubf + row0 * DINNER + d;
  const float* Bp = xdbl + row0 * 128 + 64;
  float h[16];
#pragma unroll
  for (int n = 0; n < 16; ++n) h[n] = 0.f;
  float sdt = 0.f;
  float dt_c = bf2f(dtp[0]);
  float uu_c = bf2f(up[0]);
  const float4* B4 = (const float4*)Bp;
  float4 b0c = B4[0], b1c = B4[1], b2c = B4[2], b3c = B4[3];
  for (int i = 0; i < 64; ++i) {
    float dt_n = dt_c, uu_n = uu_c;
    float4 b0n = b0c, b1n = b1c, b2n = b2c, b3n = b3c;
    if (i < 63) {
      dt_n = bf2f(dtp[(size_t)(i + 1) * DINNER]);
      uu_n = bf2f(up[(size_t)(i + 1) * DINNER]);
      const float4* B4n = (const float4*)(Bp + (size_t)(i + 1) * 128);
      b0n = B4n[0]; b1n = B4n[1]; b2n = B4n[2]; b3n = B4n[3];
    }
    float dtu = dt_c * uu_c;
    sdt += dt_c;
    float Bf[16] = {b0c.x, b0c.y, b0c.z, b0c.w, b1c.x, b1c.y, b1c.z, b1c.w,
                    b2c.x, b2c.y, b2c.z, b2c.w, b3c.x, b3c.y, b3c.z, b3c.w};
    float av[16];
    compute_a(dt_c, An, fast, av);
#pragma unroll
    for (int n = 0; n < 16; ++n) h[n] = av[n] * h[n] + dtu * Bf[n];
    dt_c = dt_n; uu_c = uu_n;
    b0c = b0n; b1c = b1n; b2c = b2n; b3c = b3n;
  }
  size_t idx = (size_t)c * 65536 + ((size_t)b * DINNER + d) * 16;
  float4* P4 = (float4*)(P + idx);
  float4* H4 = (float4*)(H + idx);
#pragma unroll
  for (int q = 0; q < 4; ++q) {
    P4[q] = make_float4(__expf(An[q * 4 + 0] * sdt), __expf(An[q * 4 + 1] * sdt),
                        __expf(An[q * 4 + 2] * sdt), __expf(An[q * 4 + 3] * sdt));
    H4[q] = make_float4(h[q * 4], h[q * 4 + 1], h[q * 4 + 2], h[q * 4 + 3]);
  }
}

// ---------------- scan pass 2 ----------------
__global__ __launch_bounds__(256) void scan2(const float* __restrict__ P,
                                             const float* __restrict__ H,
                                             float* __restrict__ Hinit) {
  int i = blockIdx.x * 256 + threadIdx.x;
  float h = 0.f;
  for (int c = 0; c < 64; ++c) {
    Hinit[(size_t)c * 65536 + i] = h;
    h = P[(size_t)c * 65536 + i] * h + H[(size_t)c * 65536 + i];
  }
}

// ---------------- scan pass 3: replay + D-term + gate, software-pipelined loads ----------
__global__ __launch_bounds__(256) void scan3(const u16* __restrict__ dtbf,
                                             const u16* __restrict__ ubf,
                                             const float* __restrict__ xdbl,
                                             const float* __restrict__ A_log,
                                             const float* __restrict__ Dp,
                                             const u16* __restrict__ xzbf,
                                             const float* __restrict__ Hinit,
                                             u16* __restrict__ ybf) {
  int d = blockIdx.x * 256 + threadIdx.x;
  int b = blockIdx.y, c = blockIdx.z;
  size_t row0 = (size_t)b * LSEQ + c * 64;
  float An[16];
  bool fast;
  load_An(A_log, d, An, fast);
  const u16* dtp = dtbf + row0 * DINNER + d;
  const u16* up = ubf + row0 * DINNER + d;
  const float* Bp = xdbl + row0 * 128 + 64;
  const float* Cp = xdbl + row0 * 128 + 80;
  const u16* gp = xzbf + row0 * 4096 + DINNER + d;
  u16* yp = ybf + row0 * DINNER + d;
  float Dv = Dp[d];
  float h[16];
  {
    const float4* Hi4 = (const float4*)(Hinit + (size_t)c * 65536 + ((size_t)b * DINNER + d) * 16);
#pragma unroll
    for (int q = 0; q < 4; ++q) {
      float4 hv = Hi4[q];
      h[q * 4 + 0] = hv.x; h[q * 4 + 1] = hv.y; h[q * 4 + 2] = hv.z; h[q * 4 + 3] = hv.w;
    }
  }
  float dt_c = bf2f(dtp[0]);
  float uu_c = bf2f(up[0]);
  float g_c = bf2f(gp[0]);
  const float4* B4 = (const float4*)Bp;
  const float4* C4 = (const float4*)Cp;
  float4 b0c = B4[0], b1c = B4[1], b2c = B4[2], b3c = B4[3];
  float4 c0c = C4[0], c1c = C4[1], c2c = C4[2], c3c = C4[3];
  for (int i = 0; i < 64; ++i) {
    float dt_n = dt_c, uu_n = uu_c, g_n = g_c;
    float4 b0n = b0c, b1n = b1c, b2n = b2c, b3n = b3c;
    float4 c0n = c0c, c1n = c1c, c2n = c2c, c3n = c3c;
    if (i < 63) {
      dt_n = bf2f(dtp[(size_t)(i + 1) * DINNER]);
      uu_n = bf2f(up[(size_t)(i + 1) * DINNER]);
      g_n = bf2f(gp[(size_t)(i + 1) * 4096]);
      const float4* B4n = (const float4*)(Bp + (size_t)(i + 1) * 128);
      const float4* C4n = (const float4*)(Cp + (size_t)(i + 1) * 128);
      b0n = B4n[0]; b1n = B4n[1]; b2n = B4n[2]; b3n = B4n[3];
      c0n = C4n[0]; c1n = C4n[1]; c2n = C4n[2]; c3n = C4n[3];
    }
    float dtu = dt_c * uu_c;
    float Bf[16] = {b0c.x, b0c.y, b0c.z, b0c.w, b1c.x, b1c.y, b1c.z, b1c.w,
                    b2c.x, b2c.y, b2c.z, b2c.w, b3c.x, b3c.y, b3c.z, b3c.w};
    float Cf[16] = {c0c.x, c0c.y, c0c.z, c0c.w, c1c.x, c1c.y, c1c.z, c1c.w,
                    c2c.x, c2c.y, c2c.z, c2c.w, c3c.x, c3c.y, c3c.z, c3c.w};
    float av[16];
    compute_a(dt_c, An, fast, av);
    float y = 0.f;
#pragma unroll
    for (int n = 0; n < 16; ++n) {
      h[n] = av[n] * h[n] + dtu * Bf[n];
      y += h[n] * Cf[n];
    }
    yp[(size_t)i * DINNER] = f2bf((y + uu_c * Dv) * g_c);
    dt_c = dt_n; uu_c = uu_n; g_c = g_n;
    b0c = b0n; b1c = b1n; b2c = b2n; b3c = b3n;
    c0c = c0n; c1c = c1n; c2c = c2n; c3c = c3n;
  }
}

extern "C" void kernel_launch(void* const* d_in, const int* in_sizes, int n_in,
                              void* d_out, int out_size, void* d_ws, size_t ws_size,
                              hipStream_t stream) {
  const float* x = (const float*)d_in[0];
  const float* nw = (const float*)d_in[1];
  const float* nb = (const float*)d_in[2];
  const float* W_in = (const float*)d_in[3];
  const float* convw = (const float*)d_in[4];
  const float* convb = (const float*)d_in[5];
  const float* W_x = (const float*)d_in[6];
  const float* W_dt = (const float*)d_in[7];
  const float* b_dt = (const float*)d_in[8];
  const float* A_log = (const float*)d_in[9];
  const float* Dp = (const float*)d_in[10];
  const float* W_out = (const float*)d_in[11];
  float* out = (float*)d_out;

  char* wp = (char*)d_ws;
  auto alloc = [&](size_t bytes) {
    char* p = wp;
    wp += (bytes + 255) & ~(size_t)255;
    return p;
  };
  u16* xz_bf = (u16*)alloc((size_t)8192 * 4096 * 2);     // x half raw, z half silu'd
  u16* xconv_bf = (u16*)alloc((size_t)8192 * 2048 * 2);  // u
  u16* xn_bf = (u16*)alloc((size_t)8192 * 1024 * 2);
  float* xdbl = (float*)alloc((size_t)8192 * 128 * 4);
  u16* dt_bf = (u16*)alloc((size_t)8192 * 2048 * 2);     // softplus'd dt
  u16* dtlow_bf = (u16*)alloc((size_t)8192 * 64 * 2);
  u16* Wint = (u16*)alloc((size_t)4096 * 1024 * 2);
  u16* Wxt = (u16*)alloc((size_t)128 * 2048 * 2);
  u16* Wdtt = (u16*)alloc((size_t)2048 * 64 * 2);
  u16* Woutt = (u16*)alloc((size_t)1024 * 2048 * 2);
  float* P = (float*)alloc((size_t)64 * 65536 * 4);
  float* H = (float*)alloc((size_t)64 * 65536 * 4);
  float* Hinit = (float*)alloc((size_t)64 * 65536 * 4);
  // overlays:
  float* xdbl_part = (float*)P;  // split-K partials for W_x gemm, dead before scan1
  u16* y_bf = (u16*)P;           // scan3 output over P+H (P,H dead after scan2)

  // weight prep (B^T bf16), single fused launch
  tc_all<<<6528, 256, 0, stream>>>(W_in, W_x, W_dt, W_out, Wint, Wxt, Wdtt, Woutt);

  ln_kernel<<<8192, 256, 0, stream>>>(x, nw, nb, xn_bf);
  // xz = xn @ W_in, z-half silu'd in epilogue  (256^2 8-phase)
  gemm8p<1, 2><<<dim3(16, 32), 512, 0, stream>>>(xn_bf, Wint, xz_bf, nullptr,
                                                 8192, 4096, 1024, 2048);
  conv_silu<<<dim3(4, 512, 2), 256, 0, stream>>>(xz_bf, convw, convb, xconv_bf);
  // x_dbl = x_conv @ W_x : split-K x8 partials, then reduce (+ dt_low bf16 side-write)
  gemm_bt<0, 0, 1><<<dim3(1, 64, 8), 256, 0, stream>>>(xconv_bf, Wxt, xdbl_part, nullptr,
                                                       8192, 128, 256, 2048, 0);
  reduce_xdbl<<<4096, 256, 0, stream>>>(xdbl_part, xdbl, dtlow_bf);
  // dt = softplus(dt_low @ W_dt + b_dt)
  gemm_bt<1, 3, 0><<<dim3(16, 64), 256, 0, stream>>>(dtlow_bf, Wdtt, dt_bf, b_dt,
                                                     8192, 2048, 64, 64, 0);
  scan1<<<dim3(8, 2, 64), 256, 0, stream>>>(dt_bf, xconv_bf, xdbl, A_log, P, H);
  scan2<<<256, 256, 0, stream>>>(P, H, Hinit);
  scan3<<<dim3(8, 2, 64), 256, 0, stream>>>(dt_bf, xconv_bf, xdbl, A_log, Dp, xz_bf,
                                            Hinit, y_bf);
  // out = residual + y @ W_out  (128x256 tile, full machine in one round)
  gemm128_res<<<dim3(4, 64), 512, 0, stream>>>(y_bf, Woutt, out, x, 8192, 1024, 2048);
}